// Round 4
// baseline (913.779 us; speedup 1.0000x reference)
//
#include <hip/hip_runtime.h>
#include <cstddef>

#define LN_EPS 1e-5f

__device__ inline float4 ld4(const float* p) { return *reinterpret_cast<const float4*>(p); }
__device__ inline void st4(float* p, float4 v) { *reinterpret_cast<float4*>(p) = v; }

// ---- single-use group barrier (64 blocks), device-scope. Counter must be 0 before first use.
__device__ __forceinline__ void gbar(unsigned* c) {
  __syncthreads();  // drains each wave's vmem (compiler emits vmcnt(0) before s_barrier)
  if (threadIdx.x == 0) {
    __threadfence();  // agent-scope release
    __hip_atomic_fetch_add(c, 1u, __ATOMIC_ACQ_REL, __HIP_MEMORY_SCOPE_AGENT);
    for (int it = 0; it < (1 << 22); ++it) {
      if (__hip_atomic_load(c, __ATOMIC_ACQUIRE, __HIP_MEMORY_SCOPE_AGENT) >= 64u) break;
      __builtin_amdgcn_s_sleep(8);
    }
    __threadfence();  // agent-scope acquire (invalidate L1/L2 as needed)
  }
  __syncthreads();
}

// ---- 64x64 tile GEMM unit, 4x4 micro, KSTEP 16. row0 is a GLOBAL row index.
// bias!=nullptr: dst[row][c] = acc + bias[c]. else: dst is partial base (kz offset pre-added).
__device__ __forceinline__ void gemm_dev(float* lds, const float* __restrict__ A,
                                         const float* __restrict__ W,
                                         const float* __restrict__ bias,
                                         float* __restrict__ dst,
                                         int K, int chunk, int row0, int col0, int k0) {
  float* At = lds;          // [16][68] transposed A tile
  float* Ws = lds + 1088;   // [16][68]
  const int tid = threadIdx.x;
  const int tx = tid & 15, ty = tid >> 4;
  float acc[4][4] = {{0.f}};
  const int arow = tid >> 2;
  const int ak4 = (tid & 3) * 4;
  const int wk = tid >> 4;
  const int wc4 = (tid & 15) * 4;
  for (int ks = 0; ks < chunk; ks += 16) {
    float4 av = ld4(&A[(size_t)(row0 + arow) * K + k0 + ks + ak4]);
    float4 wv = ld4(&W[(size_t)(k0 + ks + wk) * 256 + col0 + wc4]);
    __syncthreads();
    At[(ak4 + 0) * 68 + arow] = av.x;
    At[(ak4 + 1) * 68 + arow] = av.y;
    At[(ak4 + 2) * 68 + arow] = av.z;
    At[(ak4 + 3) * 68 + arow] = av.w;
    st4(&Ws[wk * 68 + wc4], wv);
    __syncthreads();
#pragma unroll
    for (int kk = 0; kk < 16; ++kk) {
      float4 a = ld4(&At[kk * 68 + ty * 4]);
      float4 w = ld4(&Ws[kk * 68 + tx * 4]);
      acc[0][0] = fmaf(a.x, w.x, acc[0][0]); acc[0][1] = fmaf(a.x, w.y, acc[0][1]);
      acc[0][2] = fmaf(a.x, w.z, acc[0][2]); acc[0][3] = fmaf(a.x, w.w, acc[0][3]);
      acc[1][0] = fmaf(a.y, w.x, acc[1][0]); acc[1][1] = fmaf(a.y, w.y, acc[1][1]);
      acc[1][2] = fmaf(a.y, w.z, acc[1][2]); acc[1][3] = fmaf(a.y, w.w, acc[1][3]);
      acc[2][0] = fmaf(a.z, w.x, acc[2][0]); acc[2][1] = fmaf(a.z, w.y, acc[2][1]);
      acc[2][2] = fmaf(a.z, w.z, acc[2][2]); acc[2][3] = fmaf(a.z, w.w, acc[2][3]);
      acc[3][0] = fmaf(a.w, w.x, acc[3][0]); acc[3][1] = fmaf(a.w, w.y, acc[3][1]);
      acc[3][2] = fmaf(a.w, w.z, acc[3][2]); acc[3][3] = fmaf(a.w, w.w, acc[3][3]);
    }
  }
  if (bias) {
    float4 b4 = ld4(&bias[col0 + tx * 4]);
#pragma unroll
    for (int i = 0; i < 4; ++i) {
      float4 o;
      o.x = acc[i][0] + b4.x; o.y = acc[i][1] + b4.y;
      o.z = acc[i][2] + b4.z; o.w = acc[i][3] + b4.w;
      st4(&dst[(size_t)(row0 + ty * 4 + i) * 256 + col0 + tx * 4], o);
    }
  } else {
#pragma unroll
    for (int i = 0; i < 4; ++i) {
      float4 o = {acc[i][0], acc[i][1], acc[i][2], acc[i][3]};
      st4(&dst[(size_t)(row0 + ty * 4 + i) * 256 + col0 + tx * 4], o);
    }
  }
}

// ---- transposed-A GEMM unit (upd partials), batch gb.
__device__ __forceinline__ void gemmt_dev(float* lds, const float* __restrict__ pred,
                                          const float* __restrict__ nt,
                                          float* __restrict__ pp,
                                          int gb, int n0, int col0, int k0) {
  float* At = lds;          // [16][68] : [ee][n]
  float* Ws = lds + 1088;   // [16][68] : [ee][c]
  const int tid = threadIdx.x;
  const int tx = tid & 15, ty = tid >> 4;
  const float* Ab = pred + ((size_t)gb << 16);
  const float* Bb = nt + ((size_t)gb << 16);
  float acc[4][4] = {{0.f}};
  const int ee = tid >> 4;
  const int q4 = (tid & 15) * 4;
  for (int ks = 0; ks < 64; ks += 16) {
    float4 av = ld4(&Ab[((size_t)(k0 + ks + ee) << 8) + n0 + q4]);
    float4 wv = ld4(&Bb[((size_t)(k0 + ks + ee) << 8) + col0 + q4]);
    __syncthreads();
    st4(&At[ee * 68 + q4], av);
    st4(&Ws[ee * 68 + q4], wv);
    __syncthreads();
#pragma unroll
    for (int kk = 0; kk < 16; ++kk) {
      float4 a = ld4(&At[kk * 68 + ty * 4]);
      float4 w = ld4(&Ws[kk * 68 + tx * 4]);
      acc[0][0] = fmaf(a.x, w.x, acc[0][0]); acc[0][1] = fmaf(a.x, w.y, acc[0][1]);
      acc[0][2] = fmaf(a.x, w.z, acc[0][2]); acc[0][3] = fmaf(a.x, w.w, acc[0][3]);
      acc[1][0] = fmaf(a.y, w.x, acc[1][0]); acc[1][1] = fmaf(a.y, w.y, acc[1][1]);
      acc[1][2] = fmaf(a.y, w.z, acc[1][2]); acc[1][3] = fmaf(a.y, w.w, acc[1][3]);
      acc[2][0] = fmaf(a.z, w.x, acc[2][0]); acc[2][1] = fmaf(a.z, w.y, acc[2][1]);
      acc[2][2] = fmaf(a.z, w.z, acc[2][2]); acc[2][3] = fmaf(a.z, w.w, acc[2][3]);
      acc[3][0] = fmaf(a.w, w.x, acc[3][0]); acc[3][1] = fmaf(a.w, w.y, acc[3][1]);
      acc[3][2] = fmaf(a.w, w.z, acc[3][2]); acc[3][3] = fmaf(a.w, w.w, acc[3][3]);
    }
  }
#pragma unroll
  for (int i = 0; i < 4; ++i) {
    float4 o = {acc[i][0], acc[i][1], acc[i][2], acc[i][3]};
    st4(&pp[(((size_t)gb << 8) + n0 + ty * 4 + i) * 256 + col0 + tx * 4], o);
  }
}

// ---- fused adjacency tile (32x32), batch gb.
__device__ __forceinline__ void adj_dev(float* lds, const float* __restrict__ part,
                                        const float* __restrict__ incold,
                                        const float* __restrict__ wi,
                                        const float* __restrict__ bi,
                                        const float* __restrict__ bx,
                                        const float* __restrict__ wsv,
                                        const float* __restrict__ bs,
                                        float* pred, float* pred2,
                                        int gb, int n0, int e0) {
  float* tn = lds;
  float* te = lds + 32 * 132;
  const int tid = threadIdx.x;
  const size_t rb = (size_t)gb * 256;
  const int tx = tid & 15, ty = tid >> 4;
  float incv[2][2], acc[2][2];
#pragma unroll
  for (int j = 0; j < 2; ++j)
#pragma unroll
    for (int i = 0; i < 2; ++i) {
      incv[j][i] = incold[((rb + e0 + ty + 16 * j) << 8) + n0 + tx + 16 * i];
      acc[j][i] = 0.f;
    }
  for (int dh = 0; dh < 256; dh += 128) {
    __syncthreads();
#pragma unroll
    for (int s = 0; s < 4; ++s) {
      int idx = tid + s * 256;
      int row = idx >> 5;
      int d = dh + (idx & 31) * 4;
      float4 bxv = ld4(&bx[d]);
      {
        size_t o = ((rb + n0 + row) << 8) + d;
        float4 p0 = ld4(&part[o]);
        float4 p1 = ld4(&part[o + 262144]);
        float4 p2 = ld4(&part[o + 524288]);
        float4 p3 = ld4(&part[o + 786432]);
        float4 v;
        v.x = p0.x + p1.x + p2.x + p3.x + bxv.x;
        v.y = p0.y + p1.y + p2.y + p3.y + bxv.y;
        v.z = p0.z + p1.z + p2.z + p3.z + bxv.z;
        v.w = p0.w + p1.w + p2.w + p3.w + bxv.w;
        st4(&tn[row * 132 + (d - dh)], v);
      }
      {
        size_t o = ((rb + e0 + row) << 8) + d;
        float4 p0 = ld4(&part[o]);
        float4 p1 = ld4(&part[o + 262144]);
        float4 p2 = ld4(&part[o + 524288]);
        float4 p3 = ld4(&part[o + 786432]);
        float4 bv = ld4(&bi[d]);
        float4 v;
        v.x = p0.x + p1.x + p2.x + p3.x + bxv.x + bv.x;
        v.y = p0.y + p1.y + p2.y + p3.y + bxv.y + bv.y;
        v.z = p0.z + p1.z + p2.z + p3.z + bxv.z + bv.z;
        v.w = p0.w + p1.w + p2.w + p3.w + bxv.w + bv.w;
        st4(&te[row * 132 + (d - dh)], v);
      }
    }
    __syncthreads();
#pragma unroll 4
    for (int dl = 0; dl < 128; dl += 4) {
      float4 wiq = ld4(&wi[dh + dl]);
      float4 wsq = ld4(&wsv[dh + dl]);
      float4 xn0 = ld4(&tn[tx * 132 + dl]);
      float4 xn1 = ld4(&tn[(tx + 16) * 132 + dl]);
      float4 xe0 = ld4(&te[ty * 132 + dl]);
      float4 xe1 = ld4(&te[(ty + 16) * 132 + dl]);
#pragma unroll
      for (int j = 0; j < 2; ++j) {
        float4 xe = j ? xe1 : xe0;
#pragma unroll
        for (int i = 0; i < 2; ++i) {
          float4 xn = i ? xn1 : xn0;
          float u;
          u = fmaf(incv[j][i], wiq.x, xn.x + xe.x); u = fmaxf(u, 0.f); acc[j][i] = fmaf(u, wsq.x, acc[j][i]);
          u = fmaf(incv[j][i], wiq.y, xn.y + xe.y); u = fmaxf(u, 0.f); acc[j][i] = fmaf(u, wsq.y, acc[j][i]);
          u = fmaf(incv[j][i], wiq.z, xn.z + xe.z); u = fmaxf(u, 0.f); acc[j][i] = fmaf(u, wsq.z, acc[j][i]);
          u = fmaf(incv[j][i], wiq.w, xn.w + xe.w); u = fmaxf(u, 0.f); acc[j][i] = fmaf(u, wsq.w, acc[j][i]);
        }
      }
    }
  }
  const float b0 = bs[0];
#pragma unroll
  for (int j = 0; j < 2; ++j)
#pragma unroll
    for (int i = 0; i < 2; ++i) {
      float s = acc[j][i] + b0;
      float v = 1.f / (1.f + __expf(-s));
      size_t o = ((rb + e0 + ty + 16 * j) << 8) + n0 + tx + 16 * i;
      pred[o] = v;
      if (pred2) pred2[o] = v;
    }
}

__device__ __forceinline__ void wred2(float& s, float& q) {
#pragma unroll
  for (int off = 32; off; off >>= 1) {
    s += __shfl_xor(s, off);
    q += __shfl_xor(q, off);
  }
}

// ---- reduce upd partials + LN(concat) -> h. 64 blocks x 4 rows (batch gb).
__device__ __forceinline__ void gredln768_dev(const float* __restrict__ part,
                                              const float* __restrict__ x_in,
                                              const float* __restrict__ nt,
                                              const float* __restrict__ g,
                                              const float* __restrict__ be,
                                              float* __restrict__ h, int gb, int vb) {
  const int row = gb * 256 + vb * 4 + (threadIdx.x >> 6);
  const int lane = threadIdx.x & 63;
  const int c4 = lane * 4;
  const size_t ro = (size_t)row * 256 + c4;
  float4 u = ld4(&part[ro]);
  float4 u1 = ld4(&part[ro + 262144]);
  float4 u2 = ld4(&part[ro + 524288]);
  float4 u3 = ld4(&part[ro + 786432]);
  u.x += u1.x + u2.x + u3.x;
  u.y += u1.y + u2.y + u3.y;
  u.z += u1.z + u2.z + u3.z;
  u.w += u1.w + u2.w + u3.w;
  float4 xi = ld4(&x_in[ro]);
  float4 nv = ld4(&nt[ro]);
  float s = xi.x + xi.y + xi.z + xi.w + nv.x + nv.y + nv.z + nv.w + u.x + u.y + u.z + u.w;
  float sq = xi.x * xi.x + xi.y * xi.y + xi.z * xi.z + xi.w * xi.w
           + nv.x * nv.x + nv.y * nv.y + nv.z * nv.z + nv.w * nv.w
           + u.x * u.x + u.y * u.y + u.z * u.z + u.w * u.w;
  wred2(s, sq);
  float mu = s * (1.f / 768.f);
  float rs = rsqrtf(sq * (1.f / 768.f) - mu * mu + LN_EPS);
  float* hr = h + (size_t)row * 768;
  {
    float4 g4 = ld4(&g[c4]), b4 = ld4(&be[c4]), o;
    o.x = (xi.x - mu) * rs * g4.x + b4.x;
    o.y = (xi.y - mu) * rs * g4.y + b4.y;
    o.z = (xi.z - mu) * rs * g4.z + b4.z;
    o.w = (xi.w - mu) * rs * g4.w + b4.w;
    st4(&hr[c4], o);
  }
  {
    float4 g4 = ld4(&g[256 + c4]), b4 = ld4(&be[256 + c4]), o;
    o.x = (nv.x - mu) * rs * g4.x + b4.x;
    o.y = (nv.y - mu) * rs * g4.y + b4.y;
    o.z = (nv.z - mu) * rs * g4.z + b4.z;
    o.w = (nv.w - mu) * rs * g4.w + b4.w;
    st4(&hr[256 + c4], o);
  }
  {
    float4 g4 = ld4(&g[512 + c4]), b4 = ld4(&be[512 + c4]), o;
    o.x = (u.x - mu) * rs * g4.x + b4.x;
    o.y = (u.y - mu) * rs * g4.y + b4.y;
    o.z = (u.z - mu) * rs * g4.z + b4.z;
    o.w = (u.w - mu) * rs * g4.w + b4.w;
    st4(&hr[512 + c4], o);
  }
}

// ---- colmean(64-col slice) + mean-linear partial. ks-th 64-k slice of Wl.
__device__ __forceinline__ void mtk_dev(float* lds, const float* __restrict__ X,
                                        const float* __restrict__ Wl,
                                        const float* __restrict__ bias,
                                        float* __restrict__ mtp, int gb, int ks, int Kd) {
  float* sm = lds;         // [256]
  float* m64 = lds + 256;  // [64]
  const int tid = threadIdx.x;
  const int col = tid & 63, q = tid >> 6;
  const float* xb = X + (size_t)(gb * 256 + q * 64) * Kd + ks * 64 + col;
  float s = 0.f;
#pragma unroll 8
  for (int r = 0; r < 64; ++r) s += xb[(size_t)r * Kd];
  sm[tid] = s;
  __syncthreads();
  if (tid < 64) m64[tid] = (sm[tid] + sm[tid + 64] + sm[tid + 128] + sm[tid + 192]) * (1.f / 256.f);
  __syncthreads();
  const int c = tid;
  float acc = (ks == 0) ? bias[c] : 0.f;
  const float* wp = Wl + (size_t)ks * 64 * 256 + c;
#pragma unroll 8
  for (int k = 0; k < 64; ++k) acc = fmaf(m64[k], wp[(size_t)k * 256], acc);
  mtp[((size_t)(ks * 4 + gb) << 8) + c] = acc;
}

// ---- reduce gemm768 partials + mt1 + relu -> h1. 64 blocks x 1024 elems (batch gb).
__device__ __forceinline__ void gred_dev(const float* __restrict__ part,
                                         const float* __restrict__ mtp,
                                         float* __restrict__ h1, int gb, int vb) {
  const size_t o = (size_t)gb * 65536 + vb * 1024 + threadIdx.x * 4;
  const int c4 = (int)(o & 255);
  float4 p0 = ld4(&part[o]);
  float4 p1 = ld4(&part[o + 262144]);
  float4 p2 = ld4(&part[o + 524288]);
  float4 p3 = ld4(&part[o + 786432]);
  float4 m = {0.f, 0.f, 0.f, 0.f};
#pragma unroll
  for (int k2 = 0; k2 < 12; ++k2) {
    float4 mv = ld4(&mtp[((size_t)(k2 * 4 + gb) << 8) + c4]);
    m.x += mv.x; m.y += mv.y; m.z += mv.z; m.w += mv.w;
  }
  float4 v;
  v.x = fmaxf(p0.x + p1.x + p2.x + p3.x + m.x, 0.f);
  v.y = fmaxf(p0.y + p1.y + p2.y + p3.y + m.y, 0.f);
  v.z = fmaxf(p0.z + p1.z + p2.z + p3.z + m.z, 0.f);
  v.w = fmaxf(p0.w + p1.w + p2.w + p3.w + m.w, 0.f);
  st4(&h1[o], v);
}

// ---- reduce gemm256 partials + mt2 + residual + LN -> dst. 64 blocks x 4 rows (batch gb).
__device__ __forceinline__ void gredln256_dev(const float* __restrict__ part,
                                              const float* __restrict__ nt,
                                              const float* __restrict__ mt2p,
                                              const float* __restrict__ g,
                                              const float* __restrict__ be,
                                              float* __restrict__ dst, int gb, int vb) {
  const int row = gb * 256 + vb * 4 + (threadIdx.x >> 6);
  const int lane = threadIdx.x & 63;
  const int c4 = lane * 4;
  const size_t ro = (size_t)row * 256 + c4;
  float4 p0 = ld4(&part[ro]);
  float4 p1 = ld4(&part[ro + 262144]);
  float4 p2 = ld4(&part[ro + 524288]);
  float4 p3 = ld4(&part[ro + 786432]);
  float4 m4 = {0.f, 0.f, 0.f, 0.f};
#pragma unroll
  for (int k2 = 0; k2 < 4; ++k2) {
    float4 mv = ld4(&mt2p[((size_t)(k2 * 4 + gb) << 8) + c4]);
    m4.x += mv.x; m4.y += mv.y; m4.z += mv.z; m4.w += mv.w;
  }
  float4 nv = ld4(&nt[ro]);
  float4 x;
  x.x = nv.x + p0.x + p1.x + p2.x + p3.x + m4.x;
  x.y = nv.y + p0.y + p1.y + p2.y + p3.y + m4.y;
  x.z = nv.z + p0.z + p1.z + p2.z + p3.z + m4.z;
  x.w = nv.w + p0.w + p1.w + p2.w + p3.w + m4.w;
  float s = x.x + x.y + x.z + x.w;
  float sq = x.x * x.x + x.y * x.y + x.z * x.z + x.w * x.w;
  wred2(s, sq);
  float mu = s * (1.f / 256.f);
  float rs = rsqrtf(sq * (1.f / 256.f) - mu * mu + LN_EPS);
  float4 g4 = ld4(&g[c4]), b4 = ld4(&be[c4]), o;
  o.x = (x.x - mu) * rs * g4.x + b4.x;
  o.y = (x.y - mu) * rs * g4.y + b4.y;
  o.z = (x.z - mu) * rs * g4.z + b4.z;
  o.w = (x.w - mu) * rs * g4.w + b4.w;
  st4(&dst[ro], o);
}

// ================= persistent mega-kernel: 256 blocks (4 groups of 64, one per batch)
__global__ __launch_bounds__(256, 1) void megak(
    const float* inputs, const float* v_t, const float* i_t,
    const float* Wp, const float* bp, const float* Wx, const float* bx,
    const float* wi, const float* bi, const float* wsv, const float* bs,
    const float* g_pre, const float* be_pre, const float* g_n, const float* be_n,
    const float* W1g, const float* W1l, const float* b1,
    const float* W2g, const float* W2l, const float* b2,
    float* out, float* wsf, unsigned* ctrs) {
  __shared__ float lds[8448];  // 33 KB: adj tiles / gemm tiles / mtk scratch
  const int gb = blockIdx.x >> 6;   // batch group 0..3
  const int vb = blockIdx.x & 63;   // block within group
  unsigned* ctr = ctrs + gb * 32;
  int slot = 0;

  float* x_in = wsf;
  float* ntA  = wsf + 262144;
  float* ntB  = wsf + 524288;
  float* h    = wsf + 786432;
  float* h1   = wsf + 1572864;
  float* part = wsf + 1835008;
  float* mt1p = wsf + 2883584;
  float* mt2p = wsf + 2895872;

  // P0: x_in = inputs @ Wp + bp (16 active blocks per group, full K=128)
  if (vb < 16) {
    int mt = vb & 3, ntile = vb >> 2;
    gemm_dev(lds, inputs, Wp, bp, x_in, 128, 128, gb * 256 + mt * 64, ntile * 64, 0);
  }
  gbar(ctr + slot++);

#pragma unroll 1
  for (int t = 0; t < 3; ++t) {
    const float* ntCur = (t == 0) ? v_t : ((t == 1) ? ntA : ntB);
    float* dstNt = (t == 2) ? (out + 786432) : ((t == 0) ? ntA : ntB);
    const float* incold = (t == 0) ? i_t : (out + (size_t)(t - 1) * 262144);
    float* pred = out + (size_t)t * 262144;
    float* pred2 = (t == 2) ? (out + 1048576) : nullptr;

    // P1: xp partials = ntCur @ Wx (K-split 4)
    {
      int mt = vb & 3, ntile = (vb >> 2) & 3, kz = vb >> 4;
      gemm_dev(lds, ntCur, Wx, nullptr, part + (size_t)kz * 262144, 256, 64,
               gb * 256 + mt * 64, ntile * 64, kz * 64);
    }
    gbar(ctr + slot++);

    // P2: adjacency -> pred
    adj_dev(lds, part, incold, wi, bi, bx, wsv, bs, pred, pred2,
            gb, (vb & 7) * 32, (vb >> 3) * 32);
    gbar(ctr + slot++);

    // P3: upd partials = pred^T @ ntCur (e-split 4)
    {
      int ntile = vb & 3, ctile = (vb >> 2) & 3, kc = vb >> 4;
      gemmt_dev(lds, pred, ntCur, part + (size_t)kc * 262144,
                gb, ntile * 64, ctile * 64, kc * 64);
    }
    gbar(ctr + slot++);

    // P4: h = LN(concat(x_in, nt, upd))
    gredln768_dev(part, x_in, ntCur, g_pre, be_pre, h, gb, vb);
    gbar(ctr + slot++);

    // P5||P6: gemm768 partials = h @ W1g; blocks 0..11 also mt1 partials
    {
      int mt = vb & 3, ntile = (vb >> 2) & 3, kz = vb >> 4;
      gemm_dev(lds, h, W1g, nullptr, part + (size_t)kz * 262144, 768, 192,
               gb * 256 + mt * 64, ntile * 64, kz * 192);
      __syncthreads();
      if (vb < 12) mtk_dev(lds, h, W1l, b1, mt1p, gb, vb, 768);
    }
    gbar(ctr + slot++);

    // P7: h1 = relu(sum partials + mt1)
    gred_dev(part, mt1p, h1, gb, vb);
    gbar(ctr + slot++);

    // P8||P9: gemm256 partials = h1 @ W2g; blocks 0..3 also mt2 partials
    {
      int mt = vb & 3, ntile = (vb >> 2) & 3, kz = vb >> 4;
      gemm_dev(lds, h1, W2g, nullptr, part + (size_t)kz * 262144, 256, 64,
               gb * 256 + mt * 64, ntile * 64, kz * 64);
      __syncthreads();
      if (vb < 4) mtk_dev(lds, h1, W2l, b2, mt2p, gb, vb, 256);
    }
    gbar(ctr + slot++);

    // P10: nt' = LN(nt + sum partials + mt2)
    gredln256_dev(part, ntCur, mt2p, g_n, be_n, dstNt, gb, vb);
    gbar(ctr + slot++);
  }
}

extern "C" void kernel_launch(void* const* d_in, const int* in_sizes, int n_in,
                              void* d_out, int out_size, void* d_ws, size_t ws_size,
                              hipStream_t stream) {
  (void)in_sizes; (void)n_in; (void)out_size; (void)ws_size;
  const float* inputs = (const float*)d_in[0];
  const float* v_t    = (const float*)d_in[1];
  const float* i_t    = (const float*)d_in[2];
  const float* Wp     = (const float*)d_in[3];
  const float* bp     = (const float*)d_in[4];
  const float* Wx     = (const float*)d_in[5];
  const float* bx     = (const float*)d_in[6];
  const float* wi     = (const float*)d_in[7];
  const float* bi     = (const float*)d_in[8];
  const float* ws     = (const float*)d_in[9];
  const float* bs     = (const float*)d_in[10];
  const float* g_pre  = (const float*)d_in[11];
  const float* be_pre = (const float*)d_in[12];
  const float* g_n    = (const float*)d_in[13];
  const float* be_n   = (const float*)d_in[14];
  const float* W1g    = (const float*)d_in[15];
  const float* W1l    = (const float*)d_in[16];
  const float* b1     = (const float*)d_in[17];
  const float* W2g    = (const float*)d_in[18];
  const float* W2l    = (const float*)d_in[19];
  const float* b2     = (const float*)d_in[20];
  float* out = (float*)d_out;
  float* wsf = (float*)d_ws;
  unsigned* ctrs = (unsigned*)(wsf + 2899968);  // 128 counters (4 groups x 32 slots)

  hipMemsetAsync(ctrs, 0, 128 * sizeof(unsigned), stream);
  megak<<<256, 256, 0, stream>>>(inputs, v_t, i_t, Wp, bp, Wx, bx, wi, bi, ws, bs,
                                 g_pre, be_pre, g_n, be_n, W1g, W1l, b1, W2g, W2l, b2,
                                 out, wsf, ctrs);
}

// Round 5
// 422.855 us; speedup vs baseline: 2.1610x; 2.1610x over previous
//
#include <hip/hip_runtime.h>
#include <cstddef>

#define LN_EPS 1e-5f

__device__ inline float4 ld4(const float* p) { return *reinterpret_cast<const float4*>(p); }
__device__ inline void st4(float* p, float4 v) { *reinterpret_cast<float4*>(p) = v; }

// ---- single-use group barrier (64 blocks). Counter (128B-padded slot) must be 0 before use.
// Arrival: one RELEASE fetch_add. Poll: RELAXED loads (no cache ops). Exit: one ACQUIRE load.
__device__ __forceinline__ void gbar(unsigned* c) {
  __syncthreads();
  if (threadIdx.x == 0) {
    __hip_atomic_fetch_add(c, 1u, __ATOMIC_RELEASE, __HIP_MEMORY_SCOPE_AGENT);
    for (int it = 0; it < (1 << 24); ++it) {
      if (__hip_atomic_load(c, __ATOMIC_RELAXED, __HIP_MEMORY_SCOPE_AGENT) >= 64u) break;
      __builtin_amdgcn_s_sleep(1);
    }
    (void)__hip_atomic_load(c, __ATOMIC_ACQUIRE, __HIP_MEMORY_SCOPE_AGENT);
  }
  __syncthreads();
}

// ---- 64x64 tile GEMM unit, 4x4 micro, KSTEP 16. row0 is a GLOBAL row index.
__device__ __forceinline__ void gemm_dev(float* lds, const float* __restrict__ A,
                                         const float* __restrict__ W,
                                         const float* __restrict__ bias,
                                         float* __restrict__ dst,
                                         int K, int chunk, int row0, int col0, int k0) {
  float* At = lds;          // [16][68] transposed A tile
  float* Ws = lds + 1088;   // [16][68]
  const int tid = threadIdx.x;
  const int tx = tid & 15, ty = tid >> 4;
  float acc[4][4] = {{0.f}};
  const int arow = tid >> 2;
  const int ak4 = (tid & 3) * 4;
  const int wk = tid >> 4;
  const int wc4 = (tid & 15) * 4;
  for (int ks = 0; ks < chunk; ks += 16) {
    float4 av = ld4(&A[(size_t)(row0 + arow) * K + k0 + ks + ak4]);
    float4 wv = ld4(&W[(size_t)(k0 + ks + wk) * 256 + col0 + wc4]);
    __syncthreads();
    At[(ak4 + 0) * 68 + arow] = av.x;
    At[(ak4 + 1) * 68 + arow] = av.y;
    At[(ak4 + 2) * 68 + arow] = av.z;
    At[(ak4 + 3) * 68 + arow] = av.w;
    st4(&Ws[wk * 68 + wc4], wv);
    __syncthreads();
#pragma unroll
    for (int kk = 0; kk < 16; ++kk) {
      float4 a = ld4(&At[kk * 68 + ty * 4]);
      float4 w = ld4(&Ws[kk * 68 + tx * 4]);
      acc[0][0] = fmaf(a.x, w.x, acc[0][0]); acc[0][1] = fmaf(a.x, w.y, acc[0][1]);
      acc[0][2] = fmaf(a.x, w.z, acc[0][2]); acc[0][3] = fmaf(a.x, w.w, acc[0][3]);
      acc[1][0] = fmaf(a.y, w.x, acc[1][0]); acc[1][1] = fmaf(a.y, w.y, acc[1][1]);
      acc[1][2] = fmaf(a.y, w.z, acc[1][2]); acc[1][3] = fmaf(a.y, w.w, acc[1][3]);
      acc[2][0] = fmaf(a.z, w.x, acc[2][0]); acc[2][1] = fmaf(a.z, w.y, acc[2][1]);
      acc[2][2] = fmaf(a.z, w.z, acc[2][2]); acc[2][3] = fmaf(a.z, w.w, acc[2][3]);
      acc[3][0] = fmaf(a.w, w.x, acc[3][0]); acc[3][1] = fmaf(a.w, w.y, acc[3][1]);
      acc[3][2] = fmaf(a.w, w.z, acc[3][2]); acc[3][3] = fmaf(a.w, w.w, acc[3][3]);
    }
  }
  if (bias) {
    float4 b4 = ld4(&bias[col0 + tx * 4]);
#pragma unroll
    for (int i = 0; i < 4; ++i) {
      float4 o;
      o.x = acc[i][0] + b4.x; o.y = acc[i][1] + b4.y;
      o.z = acc[i][2] + b4.z; o.w = acc[i][3] + b4.w;
      st4(&dst[(size_t)(row0 + ty * 4 + i) * 256 + col0 + tx * 4], o);
    }
  } else {
#pragma unroll
    for (int i = 0; i < 4; ++i) {
      float4 o = {acc[i][0], acc[i][1], acc[i][2], acc[i][3]};
      st4(&dst[(size_t)(row0 + ty * 4 + i) * 256 + col0 + tx * 4], o);
    }
  }
}

// ---- 64x64 GEMM with A = h1 recomputed inline: A[r][k] = relu(sum_4 part slabs + mt1[k]).
__device__ __forceinline__ void gemm_h1(float* lds, const float* __restrict__ part,
                                        const float* __restrict__ mt1p,
                                        const float* __restrict__ W,
                                        float* __restrict__ dst,
                                        int gb, int row0, int col0, int k0) {
  float* At = lds;           // [16][68]
  float* Ws = lds + 1088;    // [16][68]
  float* mt1s = lds + 2176;  // [64]
  const int tid = threadIdx.x;
  const int tx = tid & 15, ty = tid >> 4;
  if (tid < 64) {
    float s = 0.f;
#pragma unroll
    for (int k2 = 0; k2 < 12; ++k2) s += mt1p[((size_t)(k2 * 4 + gb) << 8) + k0 + tid];
    mt1s[tid] = s;
  }
  float acc[4][4] = {{0.f}};
  const int arow = tid >> 2;
  const int ak4 = (tid & 3) * 4;
  const int wk = tid >> 4;
  const int wc4 = (tid & 15) * 4;
  for (int ks = 0; ks < 64; ks += 16) {
    size_t ao = (size_t)(row0 + arow) * 256 + k0 + ks + ak4;
    float4 p0 = ld4(&part[ao]);
    float4 p1 = ld4(&part[ao + 262144]);
    float4 p2 = ld4(&part[ao + 524288]);
    float4 p3 = ld4(&part[ao + 786432]);
    float4 wv = ld4(&W[(size_t)(k0 + ks + wk) * 256 + col0 + wc4]);
    __syncthreads();
    float4 m = ld4(&mt1s[ks + ak4]);
    float4 av;
    av.x = fmaxf(p0.x + p1.x + p2.x + p3.x + m.x, 0.f);
    av.y = fmaxf(p0.y + p1.y + p2.y + p3.y + m.y, 0.f);
    av.z = fmaxf(p0.z + p1.z + p2.z + p3.z + m.z, 0.f);
    av.w = fmaxf(p0.w + p1.w + p2.w + p3.w + m.w, 0.f);
    At[(ak4 + 0) * 68 + arow] = av.x;
    At[(ak4 + 1) * 68 + arow] = av.y;
    At[(ak4 + 2) * 68 + arow] = av.z;
    At[(ak4 + 3) * 68 + arow] = av.w;
    st4(&Ws[wk * 68 + wc4], wv);
    __syncthreads();
#pragma unroll
    for (int kk = 0; kk < 16; ++kk) {
      float4 a = ld4(&At[kk * 68 + ty * 4]);
      float4 w = ld4(&Ws[kk * 68 + tx * 4]);
      acc[0][0] = fmaf(a.x, w.x, acc[0][0]); acc[0][1] = fmaf(a.x, w.y, acc[0][1]);
      acc[0][2] = fmaf(a.x, w.z, acc[0][2]); acc[0][3] = fmaf(a.x, w.w, acc[0][3]);
      acc[1][0] = fmaf(a.y, w.x, acc[1][0]); acc[1][1] = fmaf(a.y, w.y, acc[1][1]);
      acc[1][2] = fmaf(a.y, w.z, acc[1][2]); acc[1][3] = fmaf(a.y, w.w, acc[1][3]);
      acc[2][0] = fmaf(a.z, w.x, acc[2][0]); acc[2][1] = fmaf(a.z, w.y, acc[2][1]);
      acc[2][2] = fmaf(a.z, w.z, acc[2][2]); acc[2][3] = fmaf(a.z, w.w, acc[2][3]);
      acc[3][0] = fmaf(a.w, w.x, acc[3][0]); acc[3][1] = fmaf(a.w, w.y, acc[3][1]);
      acc[3][2] = fmaf(a.w, w.z, acc[3][2]); acc[3][3] = fmaf(a.w, w.w, acc[3][3]);
    }
  }
#pragma unroll
  for (int i = 0; i < 4; ++i) {
    float4 o = {acc[i][0], acc[i][1], acc[i][2], acc[i][3]};
    st4(&dst[(size_t)(row0 + ty * 4 + i) * 256 + col0 + tx * 4], o);
  }
}

// ---- transposed-A GEMM unit (upd partials), batch gb.
__device__ __forceinline__ void gemmt_dev(float* lds, const float* __restrict__ pred,
                                          const float* __restrict__ nt,
                                          float* __restrict__ pp,
                                          int gb, int n0, int col0, int k0) {
  float* At = lds;
  float* Ws = lds + 1088;
  const int tid = threadIdx.x;
  const int tx = tid & 15, ty = tid >> 4;
  const float* Ab = pred + ((size_t)gb << 16);
  const float* Bb = nt + ((size_t)gb << 16);
  float acc[4][4] = {{0.f}};
  const int ee = tid >> 4;
  const int q4 = (tid & 15) * 4;
  for (int ks = 0; ks < 64; ks += 16) {
    float4 av = ld4(&Ab[((size_t)(k0 + ks + ee) << 8) + n0 + q4]);
    float4 wv = ld4(&Bb[((size_t)(k0 + ks + ee) << 8) + col0 + q4]);
    __syncthreads();
    st4(&At[ee * 68 + q4], av);
    st4(&Ws[ee * 68 + q4], wv);
    __syncthreads();
#pragma unroll
    for (int kk = 0; kk < 16; ++kk) {
      float4 a = ld4(&At[kk * 68 + ty * 4]);
      float4 w = ld4(&Ws[kk * 68 + tx * 4]);
      acc[0][0] = fmaf(a.x, w.x, acc[0][0]); acc[0][1] = fmaf(a.x, w.y, acc[0][1]);
      acc[0][2] = fmaf(a.x, w.z, acc[0][2]); acc[0][3] = fmaf(a.x, w.w, acc[0][3]);
      acc[1][0] = fmaf(a.y, w.x, acc[1][0]); acc[1][1] = fmaf(a.y, w.y, acc[1][1]);
      acc[1][2] = fmaf(a.y, w.z, acc[1][2]); acc[1][3] = fmaf(a.y, w.w, acc[1][3]);
      acc[2][0] = fmaf(a.z, w.x, acc[2][0]); acc[2][1] = fmaf(a.z, w.y, acc[2][1]);
      acc[2][2] = fmaf(a.z, w.z, acc[2][2]); acc[2][3] = fmaf(a.z, w.w, acc[2][3]);
      acc[3][0] = fmaf(a.w, w.x, acc[3][0]); acc[3][1] = fmaf(a.w, w.y, acc[3][1]);
      acc[3][2] = fmaf(a.w, w.z, acc[3][2]); acc[3][3] = fmaf(a.w, w.w, acc[3][3]);
    }
  }
#pragma unroll
  for (int i = 0; i < 4; ++i) {
    float4 o = {acc[i][0], acc[i][1], acc[i][2], acc[i][3]};
    st4(&pp[(((size_t)gb << 8) + n0 + ty * 4 + i) * 256 + col0 + tx * 4], o);
  }
}

// ---- fused adjacency tile (32x32), batch gb.
__device__ __forceinline__ void adj_dev(float* lds, const float* __restrict__ part,
                                        const float* __restrict__ incold,
                                        const float* __restrict__ wi,
                                        const float* __restrict__ bi,
                                        const float* __restrict__ bx,
                                        const float* __restrict__ wsv,
                                        const float* __restrict__ bs,
                                        float* pred, float* pred2,
                                        int gb, int n0, int e0) {
  float* tn = lds;
  float* te = lds + 32 * 132;
  const int tid = threadIdx.x;
  const size_t rb = (size_t)gb * 256;
  const int tx = tid & 15, ty = tid >> 4;
  float incv[2][2], acc[2][2];
#pragma unroll
  for (int j = 0; j < 2; ++j)
#pragma unroll
    for (int i = 0; i < 2; ++i) {
      incv[j][i] = incold[((rb + e0 + ty + 16 * j) << 8) + n0 + tx + 16 * i];
      acc[j][i] = 0.f;
    }
  for (int dh = 0; dh < 256; dh += 128) {
    __syncthreads();
#pragma unroll
    for (int s = 0; s < 4; ++s) {
      int idx = tid + s * 256;
      int row = idx >> 5;
      int d = dh + (idx & 31) * 4;
      float4 bxv = ld4(&bx[d]);
      {
        size_t o = ((rb + n0 + row) << 8) + d;
        float4 p0 = ld4(&part[o]);
        float4 p1 = ld4(&part[o + 262144]);
        float4 p2 = ld4(&part[o + 524288]);
        float4 p3 = ld4(&part[o + 786432]);
        float4 v;
        v.x = p0.x + p1.x + p2.x + p3.x + bxv.x;
        v.y = p0.y + p1.y + p2.y + p3.y + bxv.y;
        v.z = p0.z + p1.z + p2.z + p3.z + bxv.z;
        v.w = p0.w + p1.w + p2.w + p3.w + bxv.w;
        st4(&tn[row * 132 + (d - dh)], v);
      }
      {
        size_t o = ((rb + e0 + row) << 8) + d;
        float4 p0 = ld4(&part[o]);
        float4 p1 = ld4(&part[o + 262144]);
        float4 p2 = ld4(&part[o + 524288]);
        float4 p3 = ld4(&part[o + 786432]);
        float4 bv = ld4(&bi[d]);
        float4 v;
        v.x = p0.x + p1.x + p2.x + p3.x + bxv.x + bv.x;
        v.y = p0.y + p1.y + p2.y + p3.y + bxv.y + bv.y;
        v.z = p0.z + p1.z + p2.z + p3.z + bxv.z + bv.z;
        v.w = p0.w + p1.w + p2.w + p3.w + bxv.w + bv.w;
        st4(&te[row * 132 + (d - dh)], v);
      }
    }
    __syncthreads();
#pragma unroll 4
    for (int dl = 0; dl < 128; dl += 4) {
      float4 wiq = ld4(&wi[dh + dl]);
      float4 wsq = ld4(&wsv[dh + dl]);
      float4 xn0 = ld4(&tn[tx * 132 + dl]);
      float4 xn1 = ld4(&tn[(tx + 16) * 132 + dl]);
      float4 xe0 = ld4(&te[ty * 132 + dl]);
      float4 xe1 = ld4(&te[(ty + 16) * 132 + dl]);
#pragma unroll
      for (int j = 0; j < 2; ++j) {
        float4 xe = j ? xe1 : xe0;
#pragma unroll
        for (int i = 0; i < 2; ++i) {
          float4 xn = i ? xn1 : xn0;
          float u;
          u = fmaf(incv[j][i], wiq.x, xn.x + xe.x); u = fmaxf(u, 0.f); acc[j][i] = fmaf(u, wsq.x, acc[j][i]);
          u = fmaf(incv[j][i], wiq.y, xn.y + xe.y); u = fmaxf(u, 0.f); acc[j][i] = fmaf(u, wsq.y, acc[j][i]);
          u = fmaf(incv[j][i], wiq.z, xn.z + xe.z); u = fmaxf(u, 0.f); acc[j][i] = fmaf(u, wsq.z, acc[j][i]);
          u = fmaf(incv[j][i], wiq.w, xn.w + xe.w); u = fmaxf(u, 0.f); acc[j][i] = fmaf(u, wsq.w, acc[j][i]);
        }
      }
    }
  }
  const float b0 = bs[0];
#pragma unroll
  for (int j = 0; j < 2; ++j)
#pragma unroll
    for (int i = 0; i < 2; ++i) {
      float s = acc[j][i] + b0;
      float v = 1.f / (1.f + __expf(-s));
      size_t o = ((rb + e0 + ty + 16 * j) << 8) + n0 + tx + 16 * i;
      pred[o] = v;
      if (pred2) pred2[o] = v;
    }
}

__device__ __forceinline__ void wred2(float& s, float& q) {
#pragma unroll
  for (int off = 32; off; off >>= 1) {
    s += __shfl_xor(s, off);
    q += __shfl_xor(q, off);
  }
}

// ---- reduce upd partials + LN(concat) -> h. 64 blocks x 4 rows (batch gb).
__device__ __forceinline__ void gredln768_dev(const float* __restrict__ part,
                                              const float* __restrict__ x_in,
                                              const float* __restrict__ nt,
                                              const float* __restrict__ g,
                                              const float* __restrict__ be,
                                              float* __restrict__ h, int gb, int vb) {
  const int row = gb * 256 + vb * 4 + (threadIdx.x >> 6);
  const int lane = threadIdx.x & 63;
  const int c4 = lane * 4;
  const size_t ro = (size_t)row * 256 + c4;
  float4 u = ld4(&part[ro]);
  float4 u1 = ld4(&part[ro + 262144]);
  float4 u2 = ld4(&part[ro + 524288]);
  float4 u3 = ld4(&part[ro + 786432]);
  u.x += u1.x + u2.x + u3.x;
  u.y += u1.y + u2.y + u3.y;
  u.z += u1.z + u2.z + u3.z;
  u.w += u1.w + u2.w + u3.w;
  float4 xi = ld4(&x_in[ro]);
  float4 nv = ld4(&nt[ro]);
  float s = xi.x + xi.y + xi.z + xi.w + nv.x + nv.y + nv.z + nv.w + u.x + u.y + u.z + u.w;
  float sq = xi.x * xi.x + xi.y * xi.y + xi.z * xi.z + xi.w * xi.w
           + nv.x * nv.x + nv.y * nv.y + nv.z * nv.z + nv.w * nv.w
           + u.x * u.x + u.y * u.y + u.z * u.z + u.w * u.w;
  wred2(s, sq);
  float mu = s * (1.f / 768.f);
  float rs = rsqrtf(sq * (1.f / 768.f) - mu * mu + LN_EPS);
  float* hr = h + (size_t)row * 768;
  {
    float4 g4 = ld4(&g[c4]), b4 = ld4(&be[c4]), o;
    o.x = (xi.x - mu) * rs * g4.x + b4.x;
    o.y = (xi.y - mu) * rs * g4.y + b4.y;
    o.z = (xi.z - mu) * rs * g4.z + b4.z;
    o.w = (xi.w - mu) * rs * g4.w + b4.w;
    st4(&hr[c4], o);
  }
  {
    float4 g4 = ld4(&g[256 + c4]), b4 = ld4(&be[256 + c4]), o;
    o.x = (nv.x - mu) * rs * g4.x + b4.x;
    o.y = (nv.y - mu) * rs * g4.y + b4.y;
    o.z = (nv.z - mu) * rs * g4.z + b4.z;
    o.w = (nv.w - mu) * rs * g4.w + b4.w;
    st4(&hr[256 + c4], o);
  }
  {
    float4 g4 = ld4(&g[512 + c4]), b4 = ld4(&be[512 + c4]), o;
    o.x = (u.x - mu) * rs * g4.x + b4.x;
    o.y = (u.y - mu) * rs * g4.y + b4.y;
    o.z = (u.z - mu) * rs * g4.z + b4.z;
    o.w = (u.w - mu) * rs * g4.w + b4.w;
    st4(&hr[512 + c4], o);
  }
}

// ---- colmean(64-col slice of X) + mean-linear partial (materialized X; used for h/W1l).
__device__ __forceinline__ void mtk_dev(float* lds, const float* __restrict__ X,
                                        const float* __restrict__ Wl,
                                        const float* __restrict__ bias,
                                        float* __restrict__ mtp, int gb, int ks, int Kd) {
  float* sm = lds;
  float* m64 = lds + 256;
  const int tid = threadIdx.x;
  const int col = tid & 63, q = tid >> 6;
  const float* xb = X + (size_t)(gb * 256 + q * 64) * Kd + ks * 64 + col;
  float s = 0.f;
#pragma unroll 8
  for (int r = 0; r < 64; ++r) s += xb[(size_t)r * Kd];
  sm[tid] = s;
  __syncthreads();
  if (tid < 64) m64[tid] = (sm[tid] + sm[tid + 64] + sm[tid + 128] + sm[tid + 192]) * (1.f / 256.f);
  __syncthreads();
  const int c = tid;
  float acc = (ks == 0) ? bias[c] : 0.f;
  const float* wp = Wl + (size_t)ks * 64 * 256 + c;
#pragma unroll 8
  for (int k = 0; k < 64; ++k) acc = fmaf(m64[k], wp[(size_t)k * 256], acc);
  mtp[((size_t)(ks * 4 + gb) << 8) + c] = acc;
}

// ---- colmean of h1 (recomputed inline: relu(sum part slabs + mt1)) + W2l partial.
__device__ __forceinline__ void mtk_h1(float* lds, const float* __restrict__ part,
                                       const float* __restrict__ mt1p,
                                       const float* __restrict__ Wl,
                                       const float* __restrict__ bias,
                                       float* __restrict__ mtp, int gb, int ks) {
  float* sm = lds;
  float* m64 = lds + 256;
  const int tid = threadIdx.x;
  const int col = tid & 63, q = tid >> 6;
  float mt1v = 0.f;
#pragma unroll
  for (int k2 = 0; k2 < 12; ++k2) mt1v += mt1p[((size_t)(k2 * 4 + gb) << 8) + ks * 64 + col];
  const float* pb = part + (size_t)(gb * 256 + q * 64) * 256 + ks * 64 + col;
  float s = 0.f;
#pragma unroll 4
  for (int r = 0; r < 64; ++r) {
    size_t o = (size_t)r * 256;
    float v = pb[o] + pb[o + 262144] + pb[o + 524288] + pb[o + 786432] + mt1v;
    s += fmaxf(v, 0.f);
  }
  sm[tid] = s;
  __syncthreads();
  if (tid < 64) m64[tid] = (sm[tid] + sm[tid + 64] + sm[tid + 128] + sm[tid + 192]) * (1.f / 256.f);
  __syncthreads();
  const int c = tid;
  float acc = (ks == 0) ? bias[c] : 0.f;
  const float* wp = Wl + (size_t)ks * 64 * 256 + c;
#pragma unroll 8
  for (int k = 0; k < 64; ++k) acc = fmaf(m64[k], wp[(size_t)k * 256], acc);
  mtp[((size_t)(ks * 4 + gb) << 8) + c] = acc;
}

// ---- reduce part2 partials + mt2 + residual + LN -> dst. 64 blocks x 4 rows (batch gb).
__device__ __forceinline__ void gredln256_dev(const float* __restrict__ part2,
                                              const float* __restrict__ nt,
                                              const float* __restrict__ mt2p,
                                              const float* __restrict__ g,
                                              const float* __restrict__ be,
                                              float* __restrict__ dst, int gb, int vb) {
  const int row = gb * 256 + vb * 4 + (threadIdx.x >> 6);
  const int lane = threadIdx.x & 63;
  const int c4 = lane * 4;
  const size_t ro = (size_t)row * 256 + c4;
  float4 p0 = ld4(&part2[ro]);
  float4 p1 = ld4(&part2[ro + 262144]);
  float4 p2 = ld4(&part2[ro + 524288]);
  float4 p3 = ld4(&part2[ro + 786432]);
  float4 m4 = {0.f, 0.f, 0.f, 0.f};
#pragma unroll
  for (int k2 = 0; k2 < 4; ++k2) {
    float4 mv = ld4(&mt2p[((size_t)(k2 * 4 + gb) << 8) + c4]);
    m4.x += mv.x; m4.y += mv.y; m4.z += mv.z; m4.w += mv.w;
  }
  float4 nv = ld4(&nt[ro]);
  float4 x;
  x.x = nv.x + p0.x + p1.x + p2.x + p3.x + m4.x;
  x.y = nv.y + p0.y + p1.y + p2.y + p3.y + m4.y;
  x.z = nv.z + p0.z + p1.z + p2.z + p3.z + m4.z;
  x.w = nv.w + p0.w + p1.w + p2.w + p3.w + m4.w;
  float s = x.x + x.y + x.z + x.w;
  float sq = x.x * x.x + x.y * x.y + x.z * x.z + x.w * x.w;
  wred2(s, sq);
  float mu = s * (1.f / 256.f);
  float rs = rsqrtf(sq * (1.f / 256.f) - mu * mu + LN_EPS);
  float4 g4 = ld4(&g[c4]), b4 = ld4(&be[c4]), o;
  o.x = (x.x - mu) * rs * g4.x + b4.x;
  o.y = (x.y - mu) * rs * g4.y + b4.y;
  o.z = (x.z - mu) * rs * g4.z + b4.z;
  o.w = (x.w - mu) * rs * g4.w + b4.w;
  st4(&dst[ro], o);
}

// ================= persistent mega-kernel: 256 blocks (4 groups of 64, one per batch)
__global__ __launch_bounds__(256, 1) void megak(
    const float* inputs, const float* v_t, const float* i_t,
    const float* Wp, const float* bp, const float* Wx, const float* bx,
    const float* wi, const float* bi, const float* wsv, const float* bs,
    const float* g_pre, const float* be_pre, const float* g_n, const float* be_n,
    const float* W1g, const float* W1l, const float* b1,
    const float* W2g, const float* W2l, const float* b2,
    float* out, float* wsf, unsigned* ctrs) {
  __shared__ float lds[8448];  // 33 KB
  const int gb = blockIdx.x >> 6;
  const int vb = blockIdx.x & 63;
  unsigned* ctrg = ctrs + gb * 1024;  // 32 slots x 32 u32 (128B padded)
  int slot = 0;

  float* x_in  = wsf;
  float* ntA   = wsf + 262144;
  float* ntB   = wsf + 524288;
  float* h     = wsf + 786432;   // 3 MB; dead after P5
  float* part2 = wsf + 786432;   // 4 MB = h + old-h1 region (P8/P10 only)
  float* part  = wsf + 1835008;  // 4 MB
  float* mt1p  = wsf + 2883584;
  float* mt2p  = wsf + 2895872;

  // P0: x_in = inputs @ Wp + bp
  if (vb < 16) {
    int mt = vb & 3, ntile = vb >> 2;
    gemm_dev(lds, inputs, Wp, bp, x_in, 128, 128, gb * 256 + mt * 64, ntile * 64, 0);
  }
  gbar(ctrg + (slot++ << 5));

#pragma unroll 1
  for (int t = 0; t < 3; ++t) {
    const float* ntCur = (t == 0) ? v_t : ((t == 1) ? ntA : ntB);
    float* dstNt = (t == 2) ? (out + 786432) : ((t == 0) ? ntA : ntB);
    const float* incold = (t == 0) ? i_t : (out + (size_t)(t - 1) * 262144);
    float* pred = out + (size_t)t * 262144;
    float* pred2 = (t == 2) ? (out + 1048576) : nullptr;

    // P1: xp partials = ntCur @ Wx (K-split 4)
    {
      int mt = vb & 3, ntile = (vb >> 2) & 3, kz = vb >> 4;
      gemm_dev(lds, ntCur, Wx, nullptr, part + (size_t)kz * 262144, 256, 64,
               gb * 256 + mt * 64, ntile * 64, kz * 64);
    }
    gbar(ctrg + (slot++ << 5));

    // P2: adjacency -> pred
    adj_dev(lds, part, incold, wi, bi, bx, wsv, bs, pred, pred2,
            gb, (vb & 7) * 32, (vb >> 3) * 32);
    gbar(ctrg + (slot++ << 5));

    // P3: upd partials = pred^T @ ntCur (e-split 4)
    {
      int ntile = vb & 3, ctile = (vb >> 2) & 3, kc = vb >> 4;
      gemmt_dev(lds, pred, ntCur, part + (size_t)kc * 262144,
                gb, ntile * 64, ctile * 64, kc * 64);
    }
    gbar(ctrg + (slot++ << 5));

    // P4: h = LN(concat(x_in, nt, upd))
    gredln768_dev(part, x_in, ntCur, g_pre, be_pre, h, gb, vb);
    gbar(ctrg + (slot++ << 5));

    // P5: gemm768 partials = h @ W1g; blocks 0..11 also mt1 partials
    {
      int mt = vb & 3, ntile = (vb >> 2) & 3, kz = vb >> 4;
      gemm_dev(lds, h, W1g, nullptr, part + (size_t)kz * 262144, 768, 192,
               gb * 256 + mt * 64, ntile * 64, kz * 192);
      __syncthreads();
      if (vb < 12) mtk_dev(lds, h, W1l, b1, mt1p, gb, vb, 768);
    }
    gbar(ctrg + (slot++ << 5));

    // P8: part2 partials = relu(h1 inline) @ W2g; blocks 0..3 also mt2 partials
    {
      int mt = vb & 3, ntile = (vb >> 2) & 3, kz = vb >> 4;
      gemm_h1(lds, part, mt1p, W2g, part2 + (size_t)kz * 262144,
              gb, gb * 256 + mt * 64, ntile * 64, kz * 64);
      __syncthreads();
      if (vb < 4) mtk_h1(lds, part, mt1p, W2l, b2, mt2p, gb, vb);
    }
    gbar(ctrg + (slot++ << 5));

    // P10: nt' = LN(nt + sum part2 + mt2)
    gredln256_dev(part2, ntCur, mt2p, g_n, be_n, dstNt, gb, vb);
    gbar(ctrg + (slot++ << 5));
  }
}

extern "C" void kernel_launch(void* const* d_in, const int* in_sizes, int n_in,
                              void* d_out, int out_size, void* d_ws, size_t ws_size,
                              hipStream_t stream) {
  (void)in_sizes; (void)n_in; (void)out_size; (void)ws_size;
  const float* inputs = (const float*)d_in[0];
  const float* v_t    = (const float*)d_in[1];
  const float* i_t    = (const float*)d_in[2];
  const float* Wp     = (const float*)d_in[3];
  const float* bp     = (const float*)d_in[4];
  const float* Wx     = (const float*)d_in[5];
  const float* bx     = (const float*)d_in[6];
  const float* wi     = (const float*)d_in[7];
  const float* bi     = (const float*)d_in[8];
  const float* ws     = (const float*)d_in[9];
  const float* bs     = (const float*)d_in[10];
  const float* g_pre  = (const float*)d_in[11];
  const float* be_pre = (const float*)d_in[12];
  const float* g_n    = (const float*)d_in[13];
  const float* be_n   = (const float*)d_in[14];
  const float* W1g    = (const float*)d_in[15];
  const float* W1l    = (const float*)d_in[16];
  const float* b1     = (const float*)d_in[17];
  const float* W2g    = (const float*)d_in[18];
  const float* W2l    = (const float*)d_in[19];
  const float* b2     = (const float*)d_in[20];
  float* out = (float*)d_out;
  float* wsf = (float*)d_ws;
  unsigned* ctrs = (unsigned*)(wsf + 2899968);  // 4 groups x 32 slots x 32 u32 = 16 KB

  hipMemsetAsync(ctrs, 0, 4096 * sizeof(unsigned), stream);
  megak<<<256, 256, 0, stream>>>(inputs, v_t, i_t, Wp, bp, Wx, bx, wi, bi, ws, bs,
                                 g_pre, be_pre, g_n, be_n, W1g, W1l, b1, W2g, W2l, b2,
                                 out, wsf, ctrs);
}

// Round 6
// 219.117 us; speedup vs baseline: 4.1703x; 1.9298x over previous
//
#include <hip/hip_runtime.h>
#include <cstddef>

#define LN_EPS 1e-5f

__device__ inline float4 ld4(const float* p) { return *reinterpret_cast<const float4*>(p); }
__device__ inline void st4(float* p, float4 v) { *reinterpret_cast<float4*>(p) = v; }

// ---- 64x64 tile GEMM unit, 4x4 micro, KSTEP 16. row0 is a GLOBAL row index (M=1024).
__device__ __forceinline__ void gemm_dev(float* lds, const float* __restrict__ A,
                                         const float* __restrict__ W,
                                         const float* __restrict__ bias,
                                         float* __restrict__ dst,
                                         int K, int chunk, int row0, int col0, int k0) {
  float* At = lds;          // [16][68] transposed A tile
  float* Ws = lds + 1088;   // [16][68]
  const int tid = threadIdx.x;
  const int tx = tid & 15, ty = tid >> 4;
  float acc[4][4] = {{0.f}};
  const int arow = tid >> 2;
  const int ak4 = (tid & 3) * 4;
  const int wk = tid >> 4;
  const int wc4 = (tid & 15) * 4;
  for (int ks = 0; ks < chunk; ks += 16) {
    float4 av = ld4(&A[(size_t)(row0 + arow) * K + k0 + ks + ak4]);
    float4 wv = ld4(&W[(size_t)(k0 + ks + wk) * 256 + col0 + wc4]);
    __syncthreads();
    At[(ak4 + 0) * 68 + arow] = av.x;
    At[(ak4 + 1) * 68 + arow] = av.y;
    At[(ak4 + 2) * 68 + arow] = av.z;
    At[(ak4 + 3) * 68 + arow] = av.w;
    st4(&Ws[wk * 68 + wc4], wv);
    __syncthreads();
#pragma unroll
    for (int kk = 0; kk < 16; ++kk) {
      float4 a = ld4(&At[kk * 68 + ty * 4]);
      float4 w = ld4(&Ws[kk * 68 + tx * 4]);
      acc[0][0] = fmaf(a.x, w.x, acc[0][0]); acc[0][1] = fmaf(a.x, w.y, acc[0][1]);
      acc[0][2] = fmaf(a.x, w.z, acc[0][2]); acc[0][3] = fmaf(a.x, w.w, acc[0][3]);
      acc[1][0] = fmaf(a.y, w.x, acc[1][0]); acc[1][1] = fmaf(a.y, w.y, acc[1][1]);
      acc[1][2] = fmaf(a.y, w.z, acc[1][2]); acc[1][3] = fmaf(a.y, w.w, acc[1][3]);
      acc[2][0] = fmaf(a.z, w.x, acc[2][0]); acc[2][1] = fmaf(a.z, w.y, acc[2][1]);
      acc[2][2] = fmaf(a.z, w.z, acc[2][2]); acc[2][3] = fmaf(a.z, w.w, acc[2][3]);
      acc[3][0] = fmaf(a.w, w.x, acc[3][0]); acc[3][1] = fmaf(a.w, w.y, acc[3][1]);
      acc[3][2] = fmaf(a.w, w.z, acc[3][2]); acc[3][3] = fmaf(a.w, w.w, acc[3][3]);
    }
  }
  if (bias) {
    float4 b4 = ld4(&bias[col0 + tx * 4]);
#pragma unroll
    for (int i = 0; i < 4; ++i) {
      float4 o;
      o.x = acc[i][0] + b4.x; o.y = acc[i][1] + b4.y;
      o.z = acc[i][2] + b4.z; o.w = acc[i][3] + b4.w;
      st4(&dst[(size_t)(row0 + ty * 4 + i) * 256 + col0 + tx * 4], o);
    }
  } else {
#pragma unroll
    for (int i = 0; i < 4; ++i) {
      float4 o = {acc[i][0], acc[i][1], acc[i][2], acc[i][3]};
      st4(&dst[(size_t)(row0 + ty * 4 + i) * 256 + col0 + tx * 4], o);
    }
  }
}

// ---- 64x64 GEMM with A = h1 recomputed inline: A[r][k] = relu(sum_4 part slabs + mt1[k]).
__device__ __forceinline__ void gemm_h1(float* lds, const float* __restrict__ part,
                                        const float* __restrict__ mt1p,
                                        const float* __restrict__ W,
                                        float* __restrict__ dst,
                                        int gb, int row0, int col0, int k0) {
  float* At = lds;           // [16][68]
  float* Ws = lds + 1088;    // [16][68]
  float* mt1s = lds + 2176;  // [64]
  const int tid = threadIdx.x;
  const int tx = tid & 15, ty = tid >> 4;
  if (tid < 64) {
    float s = 0.f;
#pragma unroll
    for (int k2 = 0; k2 < 12; ++k2) s += mt1p[((size_t)(k2 * 4 + gb) << 8) + k0 + tid];
    mt1s[tid] = s;
  }
  float acc[4][4] = {{0.f}};
  const int arow = tid >> 2;
  const int ak4 = (tid & 3) * 4;
  const int wk = tid >> 4;
  const int wc4 = (tid & 15) * 4;
  for (int ks = 0; ks < 64; ks += 16) {
    size_t ao = (size_t)(row0 + arow) * 256 + k0 + ks + ak4;
    float4 p0 = ld4(&part[ao]);
    float4 p1 = ld4(&part[ao + 262144]);
    float4 p2 = ld4(&part[ao + 524288]);
    float4 p3 = ld4(&part[ao + 786432]);
    float4 wv = ld4(&W[(size_t)(k0 + ks + wk) * 256 + col0 + wc4]);
    __syncthreads();
    float4 m = ld4(&mt1s[ks + ak4]);
    float4 av;
    av.x = fmaxf(p0.x + p1.x + p2.x + p3.x + m.x, 0.f);
    av.y = fmaxf(p0.y + p1.y + p2.y + p3.y + m.y, 0.f);
    av.z = fmaxf(p0.z + p1.z + p2.z + p3.z + m.z, 0.f);
    av.w = fmaxf(p0.w + p1.w + p2.w + p3.w + m.w, 0.f);
    At[(ak4 + 0) * 68 + arow] = av.x;
    At[(ak4 + 1) * 68 + arow] = av.y;
    At[(ak4 + 2) * 68 + arow] = av.z;
    At[(ak4 + 3) * 68 + arow] = av.w;
    st4(&Ws[wk * 68 + wc4], wv);
    __syncthreads();
#pragma unroll
    for (int kk = 0; kk < 16; ++kk) {
      float4 a = ld4(&At[kk * 68 + ty * 4]);
      float4 w = ld4(&Ws[kk * 68 + tx * 4]);
      acc[0][0] = fmaf(a.x, w.x, acc[0][0]); acc[0][1] = fmaf(a.x, w.y, acc[0][1]);
      acc[0][2] = fmaf(a.x, w.z, acc[0][2]); acc[0][3] = fmaf(a.x, w.w, acc[0][3]);
      acc[1][0] = fmaf(a.y, w.x, acc[1][0]); acc[1][1] = fmaf(a.y, w.y, acc[1][1]);
      acc[1][2] = fmaf(a.y, w.z, acc[1][2]); acc[1][3] = fmaf(a.y, w.w, acc[1][3]);
      acc[2][0] = fmaf(a.z, w.x, acc[2][0]); acc[2][1] = fmaf(a.z, w.y, acc[2][1]);
      acc[2][2] = fmaf(a.z, w.z, acc[2][2]); acc[2][3] = fmaf(a.z, w.w, acc[2][3]);
      acc[3][0] = fmaf(a.w, w.x, acc[3][0]); acc[3][1] = fmaf(a.w, w.y, acc[3][1]);
      acc[3][2] = fmaf(a.w, w.z, acc[3][2]); acc[3][3] = fmaf(a.w, w.w, acc[3][3]);
    }
  }
#pragma unroll
  for (int i = 0; i < 4; ++i) {
    float4 o = {acc[i][0], acc[i][1], acc[i][2], acc[i][3]};
    st4(&dst[(size_t)(row0 + ty * 4 + i) * 256 + col0 + tx * 4], o);
  }
}

// ---- transposed-A GEMM unit (upd partials), batch gb.
__device__ __forceinline__ void gemmt_dev(float* lds, const float* __restrict__ pred,
                                          const float* __restrict__ nt,
                                          float* __restrict__ pp,
                                          int gb, int n0, int col0, int k0) {
  float* At = lds;
  float* Ws = lds + 1088;
  const int tid = threadIdx.x;
  const int tx = tid & 15, ty = tid >> 4;
  const float* Ab = pred + ((size_t)gb << 16);
  const float* Bb = nt + ((size_t)gb << 16);
  float acc[4][4] = {{0.f}};
  const int ee = tid >> 4;
  const int q4 = (tid & 15) * 4;
  for (int ks = 0; ks < 64; ks += 16) {
    float4 av = ld4(&Ab[((size_t)(k0 + ks + ee) << 8) + n0 + q4]);
    float4 wv = ld4(&Bb[((size_t)(k0 + ks + ee) << 8) + col0 + q4]);
    __syncthreads();
    st4(&At[ee * 68 + q4], av);
    st4(&Ws[ee * 68 + q4], wv);
    __syncthreads();
#pragma unroll
    for (int kk = 0; kk < 16; ++kk) {
      float4 a = ld4(&At[kk * 68 + ty * 4]);
      float4 w = ld4(&Ws[kk * 68 + tx * 4]);
      acc[0][0] = fmaf(a.x, w.x, acc[0][0]); acc[0][1] = fmaf(a.x, w.y, acc[0][1]);
      acc[0][2] = fmaf(a.x, w.z, acc[0][2]); acc[0][3] = fmaf(a.x, w.w, acc[0][3]);
      acc[1][0] = fmaf(a.y, w.x, acc[1][0]); acc[1][1] = fmaf(a.y, w.y, acc[1][1]);
      acc[1][2] = fmaf(a.y, w.z, acc[1][2]); acc[1][3] = fmaf(a.y, w.w, acc[1][3]);
      acc[2][0] = fmaf(a.z, w.x, acc[2][0]); acc[2][1] = fmaf(a.z, w.y, acc[2][1]);
      acc[2][2] = fmaf(a.z, w.z, acc[2][2]); acc[2][3] = fmaf(a.z, w.w, acc[2][3]);
      acc[3][0] = fmaf(a.w, w.x, acc[3][0]); acc[3][1] = fmaf(a.w, w.y, acc[3][1]);
      acc[3][2] = fmaf(a.w, w.z, acc[3][2]); acc[3][3] = fmaf(a.w, w.w, acc[3][3]);
    }
  }
#pragma unroll
  for (int i = 0; i < 4; ++i) {
    float4 o = {acc[i][0], acc[i][1], acc[i][2], acc[i][3]};
    st4(&pp[(((size_t)gb << 8) + n0 + ty * 4 + i) * 256 + col0 + tx * 4], o);
  }
}

__device__ __forceinline__ void wred2(float& s, float& q) {
#pragma unroll
  for (int off = 32; off; off >>= 1) {
    s += __shfl_xor(s, off);
    q += __shfl_xor(q, off);
  }
}

// ---- colmean(64-col slice of X) + mean-linear partial.
__device__ __forceinline__ void mtk_dev(float* lds, const float* __restrict__ X,
                                        const float* __restrict__ Wl,
                                        const float* __restrict__ bias,
                                        float* __restrict__ mtp, int gb, int ks, int Kd) {
  float* sm = lds;
  float* m64 = lds + 256;
  const int tid = threadIdx.x;
  const int col = tid & 63, q = tid >> 6;
  const float* xb = X + (size_t)(gb * 256 + q * 64) * Kd + ks * 64 + col;
  float s = 0.f;
#pragma unroll 8
  for (int r = 0; r < 64; ++r) s += xb[(size_t)r * Kd];
  sm[tid] = s;
  __syncthreads();
  if (tid < 64) m64[tid] = (sm[tid] + sm[tid + 64] + sm[tid + 128] + sm[tid + 192]) * (1.f / 256.f);
  __syncthreads();
  const int c = tid;
  float acc = (ks == 0) ? bias[c] : 0.f;
  const float* wp = Wl + (size_t)ks * 64 * 256 + c;
#pragma unroll 8
  for (int k = 0; k < 64; ++k) acc = fmaf(m64[k], wp[(size_t)k * 256], acc);
  mtp[((size_t)(ks * 4 + gb) << 8) + c] = acc;
}

// ---- colmean of h1 (recomputed inline: relu(sum part slabs + mt1)) + W2l partial.
__device__ __forceinline__ void mtk_h1(float* lds, const float* __restrict__ part,
                                       const float* __restrict__ mt1p,
                                       const float* __restrict__ Wl,
                                       const float* __restrict__ bias,
                                       float* __restrict__ mtp, int gb, int ks) {
  float* sm = lds;
  float* m64 = lds + 256;
  const int tid = threadIdx.x;
  const int col = tid & 63, q = tid >> 6;
  float mt1v = 0.f;
#pragma unroll
  for (int k2 = 0; k2 < 12; ++k2) mt1v += mt1p[((size_t)(k2 * 4 + gb) << 8) + ks * 64 + col];
  const float* pb = part + (size_t)(gb * 256 + q * 64) * 256 + ks * 64 + col;
  float s = 0.f;
#pragma unroll 4
  for (int r = 0; r < 64; ++r) {
    size_t o = (size_t)r * 256;
    float v = pb[o] + pb[o + 262144] + pb[o + 524288] + pb[o + 786432] + mt1v;
    s += fmaxf(v, 0.f);
  }
  sm[tid] = s;
  __syncthreads();
  if (tid < 64) m64[tid] = (sm[tid] + sm[tid + 64] + sm[tid + 128] + sm[tid + 192]) * (1.f / 256.f);
  __syncthreads();
  const int c = tid;
  float acc = (ks == 0) ? bias[c] : 0.f;
  const float* wp = Wl + (size_t)ks * 64 * 256 + c;
#pragma unroll 8
  for (int k = 0; k < 64; ++k) acc = fmaf(m64[k], wp[(size_t)k * 256], acc);
  mtp[((size_t)(ks * 4 + gb) << 8) + c] = acc;
}

// ================== kernels ==================

// gemm: grid (16 mtiles, 4 ntiles, KS), block 256.
__global__ __launch_bounds__(256) void k_gemm(const float* __restrict__ A,
                                              const float* __restrict__ W,
                                              const float* __restrict__ bias,
                                              float* __restrict__ dst,
                                              int K, int chunk) {
  __shared__ float lds[2176];
  float* base = bias ? dst : dst + (size_t)blockIdx.z * 262144;
  gemm_dev(lds, A, W, bias, base, K, chunk,
           blockIdx.x * 64, blockIdx.y * 64, blockIdx.z * chunk);
}

// fused adjacency: grid (8, 8, 4), block 256.
__global__ __launch_bounds__(256) void k_adj(const float* __restrict__ part,
                                             const float* __restrict__ incold,
                                             const float* __restrict__ wi,
                                             const float* __restrict__ bi,
                                             const float* __restrict__ bx,
                                             const float* __restrict__ wsv,
                                             const float* __restrict__ bs,
                                             float* __restrict__ pred,
                                             float* __restrict__ pred2) {
  __shared__ float lds[8448];
  float* tn = lds;
  float* te = lds + 32 * 132;
  const int n0 = blockIdx.x * 32, e0 = blockIdx.y * 32, gb = blockIdx.z;
  const int tid = threadIdx.x;
  const size_t rb = (size_t)gb * 256;
  const int tx = tid & 15, ty = tid >> 4;
  float incv[2][2], acc[2][2];
#pragma unroll
  for (int j = 0; j < 2; ++j)
#pragma unroll
    for (int i = 0; i < 2; ++i) {
      incv[j][i] = incold[((rb + e0 + ty + 16 * j) << 8) + n0 + tx + 16 * i];
      acc[j][i] = 0.f;
    }
  for (int dh = 0; dh < 256; dh += 128) {
    if (dh) __syncthreads();
#pragma unroll
    for (int s = 0; s < 4; ++s) {
      int idx = tid + s * 256;
      int row = idx >> 5;
      int d = dh + (idx & 31) * 4;
      float4 bxv = ld4(&bx[d]);
      {
        size_t o = ((rb + n0 + row) << 8) + d;
        float4 p0 = ld4(&part[o]);
        float4 p1 = ld4(&part[o + 262144]);
        float4 p2 = ld4(&part[o + 524288]);
        float4 p3 = ld4(&part[o + 786432]);
        float4 v;
        v.x = p0.x + p1.x + p2.x + p3.x + bxv.x;
        v.y = p0.y + p1.y + p2.y + p3.y + bxv.y;
        v.z = p0.z + p1.z + p2.z + p3.z + bxv.z;
        v.w = p0.w + p1.w + p2.w + p3.w + bxv.w;
        st4(&tn[row * 132 + (d - dh)], v);
      }
      {
        size_t o = ((rb + e0 + row) << 8) + d;
        float4 p0 = ld4(&part[o]);
        float4 p1 = ld4(&part[o + 262144]);
        float4 p2 = ld4(&part[o + 524288]);
        float4 p3 = ld4(&part[o + 786432]);
        float4 bv = ld4(&bi[d]);
        float4 v;
        v.x = p0.x + p1.x + p2.x + p3.x + bxv.x + bv.x;
        v.y = p0.y + p1.y + p2.y + p3.y + bxv.y + bv.y;
        v.z = p0.z + p1.z + p2.z + p3.z + bxv.z + bv.z;
        v.w = p0.w + p1.w + p2.w + p3.w + bxv.w + bv.w;
        st4(&te[row * 132 + (d - dh)], v);
      }
    }
    __syncthreads();
#pragma unroll 4
    for (int dl = 0; dl < 128; dl += 4) {
      float4 wiq = ld4(&wi[dh + dl]);
      float4 wsq = ld4(&wsv[dh + dl]);
      float4 xn0 = ld4(&tn[tx * 132 + dl]);
      float4 xn1 = ld4(&tn[(tx + 16) * 132 + dl]);
      float4 xe0 = ld4(&te[ty * 132 + dl]);
      float4 xe1 = ld4(&te[(ty + 16) * 132 + dl]);
#pragma unroll
      for (int j = 0; j < 2; ++j) {
        float4 xe = j ? xe1 : xe0;
#pragma unroll
        for (int i = 0; i < 2; ++i) {
          float4 xn = i ? xn1 : xn0;
          float u;
          u = fmaf(incv[j][i], wiq.x, xn.x + xe.x); u = fmaxf(u, 0.f); acc[j][i] = fmaf(u, wsq.x, acc[j][i]);
          u = fmaf(incv[j][i], wiq.y, xn.y + xe.y); u = fmaxf(u, 0.f); acc[j][i] = fmaf(u, wsq.y, acc[j][i]);
          u = fmaf(incv[j][i], wiq.z, xn.z + xe.z); u = fmaxf(u, 0.f); acc[j][i] = fmaf(u, wsq.z, acc[j][i]);
          u = fmaf(incv[j][i], wiq.w, xn.w + xe.w); u = fmaxf(u, 0.f); acc[j][i] = fmaf(u, wsq.w, acc[j][i]);
        }
      }
    }
  }
  const float b0 = bs[0];
#pragma unroll
  for (int j = 0; j < 2; ++j)
#pragma unroll
    for (int i = 0; i < 2; ++i) {
      float s = acc[j][i] + b0;
      float v = 1.f / (1.f + __expf(-s));
      size_t o = ((rb + e0 + ty + 16 * j) << 8) + n0 + tx + 16 * i;
      pred[o] = v;
      if (pred2) pred2[o] = v;
    }
}

// transposed-A GEMM: grid (4 ntiles, 4 ctiles, 16 = gb*4+kc), block 256.
__global__ __launch_bounds__(256) void k_gemmt(const float* __restrict__ pred,
                                               const float* __restrict__ nt,
                                               float* __restrict__ part) {
  __shared__ float lds[2176];
  const int gb = blockIdx.z >> 2, kc = blockIdx.z & 3;
  gemmt_dev(lds, pred, nt, part + (size_t)kc * 262144,
            gb, blockIdx.x * 64, blockIdx.y * 64, kc * 64);
}

// reduce upd partials + LN(concat) -> h. grid 256, block 256.
__global__ __launch_bounds__(256) void k_ln768(const float* __restrict__ part,
                                               const float* __restrict__ x_in,
                                               const float* __restrict__ nt,
                                               const float* __restrict__ g,
                                               const float* __restrict__ be,
                                               float* __restrict__ h) {
  const int row = blockIdx.x * 4 + (threadIdx.x >> 6);
  const int lane = threadIdx.x & 63;
  const int c4 = lane * 4;
  const size_t ro = (size_t)row * 256 + c4;
  float4 u = ld4(&part[ro]);
  float4 u1 = ld4(&part[ro + 262144]);
  float4 u2 = ld4(&part[ro + 524288]);
  float4 u3 = ld4(&part[ro + 786432]);
  u.x += u1.x + u2.x + u3.x;
  u.y += u1.y + u2.y + u3.y;
  u.z += u1.z + u2.z + u3.z;
  u.w += u1.w + u2.w + u3.w;
  float4 xi = ld4(&x_in[ro]);
  float4 nv = ld4(&nt[ro]);
  float s = xi.x + xi.y + xi.z + xi.w + nv.x + nv.y + nv.z + nv.w + u.x + u.y + u.z + u.w;
  float sq = xi.x * xi.x + xi.y * xi.y + xi.z * xi.z + xi.w * xi.w
           + nv.x * nv.x + nv.y * nv.y + nv.z * nv.z + nv.w * nv.w
           + u.x * u.x + u.y * u.y + u.z * u.z + u.w * u.w;
  wred2(s, sq);
  float mu = s * (1.f / 768.f);
  float rs = rsqrtf(sq * (1.f / 768.f) - mu * mu + LN_EPS);
  float* hr = h + (size_t)row * 768;
  {
    float4 g4 = ld4(&g[c4]), b4 = ld4(&be[c4]), o;
    o.x = (xi.x - mu) * rs * g4.x + b4.x;
    o.y = (xi.y - mu) * rs * g4.y + b4.y;
    o.z = (xi.z - mu) * rs * g4.z + b4.z;
    o.w = (xi.w - mu) * rs * g4.w + b4.w;
    st4(&hr[c4], o);
  }
  {
    float4 g4 = ld4(&g[256 + c4]), b4 = ld4(&be[256 + c4]), o;
    o.x = (nv.x - mu) * rs * g4.x + b4.x;
    o.y = (nv.y - mu) * rs * g4.y + b4.y;
    o.z = (nv.z - mu) * rs * g4.z + b4.z;
    o.w = (nv.w - mu) * rs * g4.w + b4.w;
    st4(&hr[256 + c4], o);
  }
  {
    float4 g4 = ld4(&g[512 + c4]), b4 = ld4(&be[512 + c4]), o;
    o.x = (u.x - mu) * rs * g4.x + b4.x;
    o.y = (u.y - mu) * rs * g4.y + b4.y;
    o.z = (u.z - mu) * rs * g4.z + b4.z;
    o.w = (u.w - mu) * rs * g4.w + b4.w;
    st4(&hr[512 + c4], o);
  }
}

// gemm768 (h @ W1g -> part) + mt1 partials, 1-D grid 304, block 256.
__global__ __launch_bounds__(256) void k_g768mtk(const float* __restrict__ h,
                                                 const float* __restrict__ W1g,
                                                 const float* __restrict__ W1l,
                                                 const float* __restrict__ b1,
                                                 float* __restrict__ part,
                                                 float* __restrict__ mt1p) {
  __shared__ float lds[2176];
  const int b = blockIdx.x;
  if (b < 256) {
    int mt = b & 15, ntile = (b >> 4) & 3, kz = b >> 6;
    gemm_dev(lds, h, W1g, nullptr, part + (size_t)kz * 262144, 768, 192,
             mt * 64, ntile * 64, kz * 192);
  } else {
    int idx = b - 256;           // 0..47
    mtk_dev(lds, h, W1l, b1, mt1p, idx & 3, idx >> 2, 768);
  }
}

// gemm_h1 (relu(h1) @ W2g -> part2) + mt2 partials, 1-D grid 272, block 256.
__global__ __launch_bounds__(256) void k_gh1mtk2(const float* __restrict__ part,
                                                 const float* __restrict__ mt1p,
                                                 const float* __restrict__ W2g,
                                                 const float* __restrict__ W2l,
                                                 const float* __restrict__ b2,
                                                 float* __restrict__ part2,
                                                 float* __restrict__ mt2p) {
  __shared__ float lds[2240];
  const int b = blockIdx.x;
  if (b < 256) {
    int mt = b & 15, ntile = (b >> 4) & 3, kz = b >> 6;
    gemm_h1(lds, part, mt1p, W2g, part2 + (size_t)kz * 262144,
            mt >> 2, mt * 64, ntile * 64, kz * 64);
  } else {
    int idx = b - 256;           // 0..15
    mtk_h1(lds, part, mt1p, W2l, b2, mt2p, idx & 3, idx >> 2);
  }
}

// reduce part2 partials + mt2 + residual + LN -> dst. grid 256, block 256.
__global__ __launch_bounds__(256) void k_ln256(const float* __restrict__ part2,
                                               const float* __restrict__ nt,
                                               const float* __restrict__ mt2p,
                                               const float* __restrict__ g,
                                               const float* __restrict__ be,
                                               float* __restrict__ dst) {
  const int row = blockIdx.x * 4 + (threadIdx.x >> 6);
  const int lane = threadIdx.x & 63;
  const int c4 = lane * 4;
  const int gb = row >> 8;
  const size_t ro = (size_t)row * 256 + c4;
  float4 p0 = ld4(&part2[ro]);
  float4 p1 = ld4(&part2[ro + 262144]);
  float4 p2 = ld4(&part2[ro + 524288]);
  float4 p3 = ld4(&part2[ro + 786432]);
  float4 m4 = {0.f, 0.f, 0.f, 0.f};
#pragma unroll
  for (int k2 = 0; k2 < 4; ++k2) {
    float4 mv = ld4(&mt2p[((size_t)(k2 * 4 + gb) << 8) + c4]);
    m4.x += mv.x; m4.y += mv.y; m4.z += mv.z; m4.w += mv.w;
  }
  float4 nv = ld4(&nt[ro]);
  float4 x;
  x.x = nv.x + p0.x + p1.x + p2.x + p3.x + m4.x;
  x.y = nv.y + p0.y + p1.y + p2.y + p3.y + m4.y;
  x.z = nv.z + p0.z + p1.z + p2.z + p3.z + m4.z;
  x.w = nv.w + p0.w + p1.w + p2.w + p3.w + m4.w;
  float s = x.x + x.y + x.z + x.w;
  float sq = x.x * x.x + x.y * x.y + x.z * x.z + x.w * x.w;
  wred2(s, sq);
  float mu = s * (1.f / 256.f);
  float rs = rsqrtf(sq * (1.f / 256.f) - mu * mu + LN_EPS);
  float4 g4 = ld4(&g[c4]), b4 = ld4(&be[c4]), o;
  o.x = (x.x - mu) * rs * g4.x + b4.x;
  o.y = (x.y - mu) * rs * g4.y + b4.y;
  o.z = (x.z - mu) * rs * g4.z + b4.z;
  o.w = (x.w - mu) * rs * g4.w + b4.w;
  st4(&dst[ro], o);
}

extern "C" void kernel_launch(void* const* d_in, const int* in_sizes, int n_in,
                              void* d_out, int out_size, void* d_ws, size_t ws_size,
                              hipStream_t stream) {
  (void)in_sizes; (void)n_in; (void)out_size; (void)ws_size;
  const float* inputs = (const float*)d_in[0];
  const float* v_t    = (const float*)d_in[1];
  const float* i_t    = (const float*)d_in[2];
  const float* Wp     = (const float*)d_in[3];
  const float* bp     = (const float*)d_in[4];
  const float* Wx     = (const float*)d_in[5];
  const float* bx     = (const float*)d_in[6];
  const float* wi     = (const float*)d_in[7];
  const float* bi     = (const float*)d_in[8];
  const float* ws     = (const float*)d_in[9];
  const float* bs     = (const float*)d_in[10];
  const float* g_pre  = (const float*)d_in[11];
  const float* be_pre = (const float*)d_in[12];
  const float* g_n    = (const float*)d_in[13];
  const float* be_n   = (const float*)d_in[14];
  const float* W1g    = (const float*)d_in[15];
  const float* W1l    = (const float*)d_in[16];
  const float* b1     = (const float*)d_in[17];
  const float* W2g    = (const float*)d_in[18];
  const float* W2l    = (const float*)d_in[19];
  const float* b2     = (const float*)d_in[20];
  float* out = (float*)d_out;
  float* wsf = (float*)d_ws;
  float* x_in  = wsf;                  // 1 MB
  float* ntA   = wsf + 262144;         // 1 MB
  float* ntB   = wsf + 524288;         // 1 MB
  float* h     = wsf + 786432;         // 3 MB (dead after k_g768mtk)
  float* part2 = wsf + 786432;         // 4 MB = h + old-h1 region
  float* part  = wsf + 1835008;        // 4 MB
  float* mt1p  = wsf + 2883584;        // 48 KB
  float* mt2p  = wsf + 2895872;        // 16 KB

  // P0: x_in = inputs @ Wp + bp
  k_gemm<<<dim3(16, 4, 1), 256, 0, stream>>>(inputs, Wp, bp, x_in, 128, 128);

  for (int t = 0; t < 3; ++t) {
    const float* ntCur = (t == 0) ? v_t : ((t == 1) ? ntA : ntB);
    float* dstNt = (t == 2) ? (out + 786432) : ((t == 0) ? ntA : ntB);
    const float* incold = (t == 0) ? i_t : (out + (size_t)(t - 1) * 262144);
    float* pred = out + (size_t)t * 262144;
    float* pred2 = (t == 2) ? (out + 1048576) : nullptr;

    // P1: xp partials = ntCur @ Wx (K-split 4)
    k_gemm<<<dim3(16, 4, 4), 256, 0, stream>>>(ntCur, Wx, nullptr, part, 256, 64);
    // P2: inc = sigmoid(sum_d relu(xp[n]+xp[e]+bi + inc*wi) * ws + bs)
    k_adj<<<dim3(8, 8, 4), 256, 0, stream>>>(part, incold, wi, bi, bx, ws, bs, pred, pred2);
    // P3: upd partials = pred^T @ ntCur (e-split 4)
    k_gemmt<<<dim3(4, 4, 16), 256, 0, stream>>>(pred, ntCur, part);
    // P4: h = LN(concat(x_in, nt, upd))
    k_ln768<<<256, 256, 0, stream>>>(part, x_in, ntCur, g_pre, be_pre, h);
    // P5: gemm768 partials + mt1 partials (one dispatch)
    k_g768mtk<<<304, 256, 0, stream>>>(h, W1g, W1l, b1, part, mt1p);
    // P6: part2 partials = relu(h1 inline) @ W2g + mt2 partials (one dispatch)
    k_gh1mtk2<<<272, 256, 0, stream>>>(part, mt1p, W2g, W2l, b2, part2, mt2p);
    // P7: nt' = LN(nt + sum part2 + mt2)
    k_ln256<<<256, 256, 0, stream>>>(part2, ntCur, mt2p, g_n, be_n, dstNt);
  }
}

// Round 7
// 198.587 us; speedup vs baseline: 4.6014x; 1.1034x over previous
//
#include <hip/hip_runtime.h>
#include <cstddef>

#define LN_EPS 1e-5f

__device__ inline float4 ld4(const float* p) { return *reinterpret_cast<const float4*>(p); }
__device__ inline void st4(float* p, float4 v) { *reinterpret_cast<float4*>(p) = v; }

// ---- 64x64 tile GEMM unit, 4x4 micro, KSTEP 16, software-pipelined staging.
// row0 is a GLOBAL row index (M=1024).
__device__ __forceinline__ void gemm_dev(float* lds, const float* __restrict__ A,
                                         const float* __restrict__ W,
                                         const float* __restrict__ bias,
                                         float* __restrict__ dst,
                                         int K, int chunk, int row0, int col0, int k0) {
  float* At = lds;          // [16][68] transposed A tile
  float* Ws = lds + 1088;   // [16][68]
  const int tid = threadIdx.x;
  const int tx = tid & 15, ty = tid >> 4;
  float acc[4][4] = {{0.f}};
  const int arow = tid >> 2;
  const int ak4 = (tid & 3) * 4;
  const int wk = tid >> 4;
  const int wc4 = (tid & 15) * 4;
  // prologue loads (k-step 0)
  float4 av = ld4(&A[(size_t)(row0 + arow) * K + k0 + ak4]);
  float4 wv = ld4(&W[(size_t)(k0 + wk) * 256 + col0 + wc4]);
  for (int ks = 0; ks < chunk; ks += 16) {
    __syncthreads();   // previous iteration's LDS reads complete
    At[(ak4 + 0) * 68 + arow] = av.x;
    At[(ak4 + 1) * 68 + arow] = av.y;
    At[(ak4 + 2) * 68 + arow] = av.z;
    At[(ak4 + 3) * 68 + arow] = av.w;
    st4(&Ws[wk * 68 + wc4], wv);
    __syncthreads();   // writes visible
    if (ks + 16 < chunk) {  // prefetch next k-step; latency hides under compute
      av = ld4(&A[(size_t)(row0 + arow) * K + k0 + ks + 16 + ak4]);
      wv = ld4(&W[(size_t)(k0 + ks + 16 + wk) * 256 + col0 + wc4]);
    }
#pragma unroll
    for (int kk = 0; kk < 16; ++kk) {
      float4 a = ld4(&At[kk * 68 + ty * 4]);
      float4 w = ld4(&Ws[kk * 68 + tx * 4]);
      acc[0][0] = fmaf(a.x, w.x, acc[0][0]); acc[0][1] = fmaf(a.x, w.y, acc[0][1]);
      acc[0][2] = fmaf(a.x, w.z, acc[0][2]); acc[0][3] = fmaf(a.x, w.w, acc[0][3]);
      acc[1][0] = fmaf(a.y, w.x, acc[1][0]); acc[1][1] = fmaf(a.y, w.y, acc[1][1]);
      acc[1][2] = fmaf(a.y, w.z, acc[1][2]); acc[1][3] = fmaf(a.y, w.w, acc[1][3]);
      acc[2][0] = fmaf(a.z, w.x, acc[2][0]); acc[2][1] = fmaf(a.z, w.y, acc[2][1]);
      acc[2][2] = fmaf(a.z, w.z, acc[2][2]); acc[2][3] = fmaf(a.z, w.w, acc[2][3]);
      acc[3][0] = fmaf(a.w, w.x, acc[3][0]); acc[3][1] = fmaf(a.w, w.y, acc[3][1]);
      acc[3][2] = fmaf(a.w, w.z, acc[3][2]); acc[3][3] = fmaf(a.w, w.w, acc[3][3]);
    }
  }
  if (bias) {
    float4 b4 = ld4(&bias[col0 + tx * 4]);
#pragma unroll
    for (int i = 0; i < 4; ++i) {
      float4 o;
      o.x = acc[i][0] + b4.x; o.y = acc[i][1] + b4.y;
      o.z = acc[i][2] + b4.z; o.w = acc[i][3] + b4.w;
      st4(&dst[(size_t)(row0 + ty * 4 + i) * 256 + col0 + tx * 4], o);
    }
  } else {
#pragma unroll
    for (int i = 0; i < 4; ++i) {
      float4 o = {acc[i][0], acc[i][1], acc[i][2], acc[i][3]};
      st4(&dst[(size_t)(row0 + ty * 4 + i) * 256 + col0 + tx * 4], o);
    }
  }
}

// ---- 64x64 GEMM with A = h1 recomputed inline: A[r][k] = relu(sum_4 part slabs + mt1[k]).
// Software-pipelined (prefetch 4 slabs + W).
__device__ __forceinline__ void gemm_h1(float* lds, const float* __restrict__ part,
                                        const float* __restrict__ mt1p,
                                        const float* __restrict__ W,
                                        float* __restrict__ dst,
                                        int gb, int row0, int col0, int k0) {
  float* At = lds;           // [16][68]
  float* Ws = lds + 1088;    // [16][68]
  float* mt1s = lds + 2176;  // [64]
  const int tid = threadIdx.x;
  const int tx = tid & 15, ty = tid >> 4;
  if (tid < 64) {
    float s = 0.f;
#pragma unroll
    for (int k2 = 0; k2 < 12; ++k2) s += mt1p[((size_t)(k2 * 4 + gb) << 8) + k0 + tid];
    mt1s[tid] = s;
  }
  float acc[4][4] = {{0.f}};
  const int arow = tid >> 2;
  const int ak4 = (tid & 3) * 4;
  const int wk = tid >> 4;
  const int wc4 = (tid & 15) * 4;
  size_t ao = (size_t)(row0 + arow) * 256 + k0 + ak4;
  float4 p0 = ld4(&part[ao]);
  float4 p1 = ld4(&part[ao + 262144]);
  float4 p2 = ld4(&part[ao + 524288]);
  float4 p3 = ld4(&part[ao + 786432]);
  float4 wv = ld4(&W[(size_t)(k0 + wk) * 256 + col0 + wc4]);
  for (int ks = 0; ks < 64; ks += 16) {
    __syncthreads();   // also covers mt1s availability on first pass
    float4 m = ld4(&mt1s[ks + ak4]);
    float4 av;
    av.x = fmaxf(p0.x + p1.x + p2.x + p3.x + m.x, 0.f);
    av.y = fmaxf(p0.y + p1.y + p2.y + p3.y + m.y, 0.f);
    av.z = fmaxf(p0.z + p1.z + p2.z + p3.z + m.z, 0.f);
    av.w = fmaxf(p0.w + p1.w + p2.w + p3.w + m.w, 0.f);
    At[(ak4 + 0) * 68 + arow] = av.x;
    At[(ak4 + 1) * 68 + arow] = av.y;
    At[(ak4 + 2) * 68 + arow] = av.z;
    At[(ak4 + 3) * 68 + arow] = av.w;
    st4(&Ws[wk * 68 + wc4], wv);
    __syncthreads();
    if (ks + 16 < 64) {
      size_t an = (size_t)(row0 + arow) * 256 + k0 + ks + 16 + ak4;
      p0 = ld4(&part[an]);
      p1 = ld4(&part[an + 262144]);
      p2 = ld4(&part[an + 524288]);
      p3 = ld4(&part[an + 786432]);
      wv = ld4(&W[(size_t)(k0 + ks + 16 + wk) * 256 + col0 + wc4]);
    }
#pragma unroll
    for (int kk = 0; kk < 16; ++kk) {
      float4 a = ld4(&At[kk * 68 + ty * 4]);
      float4 w = ld4(&Ws[kk * 68 + tx * 4]);
      acc[0][0] = fmaf(a.x, w.x, acc[0][0]); acc[0][1] = fmaf(a.x, w.y, acc[0][1]);
      acc[0][2] = fmaf(a.x, w.z, acc[0][2]); acc[0][3] = fmaf(a.x, w.w, acc[0][3]);
      acc[1][0] = fmaf(a.y, w.x, acc[1][0]); acc[1][1] = fmaf(a.y, w.y, acc[1][1]);
      acc[1][2] = fmaf(a.y, w.z, acc[1][2]); acc[1][3] = fmaf(a.y, w.w, acc[1][3]);
      acc[2][0] = fmaf(a.z, w.x, acc[2][0]); acc[2][1] = fmaf(a.z, w.y, acc[2][1]);
      acc[2][2] = fmaf(a.z, w.z, acc[2][2]); acc[2][3] = fmaf(a.z, w.w, acc[2][3]);
      acc[3][0] = fmaf(a.w, w.x, acc[3][0]); acc[3][1] = fmaf(a.w, w.y, acc[3][1]);
      acc[3][2] = fmaf(a.w, w.z, acc[3][2]); acc[3][3] = fmaf(a.w, w.w, acc[3][3]);
    }
  }
#pragma unroll
  for (int i = 0; i < 4; ++i) {
    float4 o = {acc[i][0], acc[i][1], acc[i][2], acc[i][3]};
    st4(&dst[(size_t)(row0 + ty * 4 + i) * 256 + col0 + tx * 4], o);
  }
}

// ---- transposed-A GEMM unit (upd partials), batch gb. Software-pipelined.
__device__ __forceinline__ void gemmt_dev(float* lds, const float* __restrict__ pred,
                                          const float* __restrict__ nt,
                                          float* __restrict__ pp,
                                          int gb, int n0, int col0, int k0) {
  float* At = lds;
  float* Ws = lds + 1088;
  const int tid = threadIdx.x;
  const int tx = tid & 15, ty = tid >> 4;
  const float* Ab = pred + ((size_t)gb << 16);
  const float* Bb = nt + ((size_t)gb << 16);
  float acc[4][4] = {{0.f}};
  const int ee = tid >> 4;
  const int q4 = (tid & 15) * 4;
  float4 av = ld4(&Ab[((size_t)(k0 + ee) << 8) + n0 + q4]);
  float4 wv = ld4(&Bb[((size_t)(k0 + ee) << 8) + col0 + q4]);
  for (int ks = 0; ks < 64; ks += 16) {
    __syncthreads();
    st4(&At[ee * 68 + q4], av);
    st4(&Ws[ee * 68 + q4], wv);
    __syncthreads();
    if (ks + 16 < 64) {
      av = ld4(&Ab[((size_t)(k0 + ks + 16 + ee) << 8) + n0 + q4]);
      wv = ld4(&Bb[((size_t)(k0 + ks + 16 + ee) << 8) + col0 + q4]);
    }
#pragma unroll
    for (int kk = 0; kk < 16; ++kk) {
      float4 a = ld4(&At[kk * 68 + ty * 4]);
      float4 w = ld4(&Ws[kk * 68 + tx * 4]);
      acc[0][0] = fmaf(a.x, w.x, acc[0][0]); acc[0][1] = fmaf(a.x, w.y, acc[0][1]);
      acc[0][2] = fmaf(a.x, w.z, acc[0][2]); acc[0][3] = fmaf(a.x, w.w, acc[0][3]);
      acc[1][0] = fmaf(a.y, w.x, acc[1][0]); acc[1][1] = fmaf(a.y, w.y, acc[1][1]);
      acc[1][2] = fmaf(a.y, w.z, acc[1][2]); acc[1][3] = fmaf(a.y, w.w, acc[1][3]);
      acc[2][0] = fmaf(a.z, w.x, acc[2][0]); acc[2][1] = fmaf(a.z, w.y, acc[2][1]);
      acc[2][2] = fmaf(a.z, w.z, acc[2][2]); acc[2][3] = fmaf(a.z, w.w, acc[2][3]);
      acc[3][0] = fmaf(a.w, w.x, acc[3][0]); acc[3][1] = fmaf(a.w, w.y, acc[3][1]);
      acc[3][2] = fmaf(a.w, w.z, acc[3][2]); acc[3][3] = fmaf(a.w, w.w, acc[3][3]);
    }
  }
#pragma unroll
  for (int i = 0; i < 4; ++i) {
    float4 o = {acc[i][0], acc[i][1], acc[i][2], acc[i][3]};
    st4(&pp[(((size_t)gb << 8) + n0 + ty * 4 + i) * 256 + col0 + tx * 4], o);
  }
}

__device__ __forceinline__ void wred2(float& s, float& q) {
#pragma unroll
  for (int off = 32; off; off >>= 1) {
    s += __shfl_xor(s, off);
    q += __shfl_xor(q, off);
  }
}

// ---- colmean(64-col slice of X) + mean-linear partial.
__device__ __forceinline__ void mtk_dev(float* lds, const float* __restrict__ X,
                                        const float* __restrict__ Wl,
                                        const float* __restrict__ bias,
                                        float* __restrict__ mtp, int gb, int ks, int Kd) {
  float* sm = lds;
  float* m64 = lds + 256;
  const int tid = threadIdx.x;
  const int col = tid & 63, q = tid >> 6;
  const float* xb = X + (size_t)(gb * 256 + q * 64) * Kd + ks * 64 + col;
  float s = 0.f;
#pragma unroll 8
  for (int r = 0; r < 64; ++r) s += xb[(size_t)r * Kd];
  sm[tid] = s;
  __syncthreads();
  if (tid < 64) m64[tid] = (sm[tid] + sm[tid + 64] + sm[tid + 128] + sm[tid + 192]) * (1.f / 256.f);
  __syncthreads();
  const int c = tid;
  float acc = (ks == 0) ? bias[c] : 0.f;
  const float* wp = Wl + (size_t)ks * 64 * 256 + c;
#pragma unroll 8
  for (int k = 0; k < 64; ++k) acc = fmaf(m64[k], wp[(size_t)k * 256], acc);
  mtp[((size_t)(ks * 4 + gb) << 8) + c] = acc;
}

// ---- colmean of h1 (recomputed inline: relu(sum part slabs + mt1)) + W2l partial.
__device__ __forceinline__ void mtk_h1(float* lds, const float* __restrict__ part,
                                       const float* __restrict__ mt1p,
                                       const float* __restrict__ Wl,
                                       const float* __restrict__ bias,
                                       float* __restrict__ mtp, int gb, int ks) {
  float* sm = lds;
  float* m64 = lds + 256;
  const int tid = threadIdx.x;
  const int col = tid & 63, q = tid >> 6;
  float mt1v = 0.f;
#pragma unroll
  for (int k2 = 0; k2 < 12; ++k2) mt1v += mt1p[((size_t)(k2 * 4 + gb) << 8) + ks * 64 + col];
  const float* pb = part + (size_t)(gb * 256 + q * 64) * 256 + ks * 64 + col;
  float s = 0.f;
#pragma unroll 4
  for (int r = 0; r < 64; ++r) {
    size_t o = (size_t)r * 256;
    float v = pb[o] + pb[o + 262144] + pb[o + 524288] + pb[o + 786432] + mt1v;
    s += fmaxf(v, 0.f);
  }
  sm[tid] = s;
  __syncthreads();
  if (tid < 64) m64[tid] = (sm[tid] + sm[tid + 64] + sm[tid + 128] + sm[tid + 192]) * (1.f / 256.f);
  __syncthreads();
  const int c = tid;
  float acc = (ks == 0) ? bias[c] : 0.f;
  const float* wp = Wl + (size_t)ks * 64 * 256 + c;
#pragma unroll 8
  for (int k = 0; k < 64; ++k) acc = fmaf(m64[k], wp[(size_t)k * 256], acc);
  mtp[((size_t)(ks * 4 + gb) << 8) + c] = acc;
}

// ================== kernels ==================

// gemm: grid (16 mtiles, 4 ntiles, KS), block 256.
__global__ __launch_bounds__(256) void k_gemm(const float* __restrict__ A,
                                              const float* __restrict__ W,
                                              const float* __restrict__ bias,
                                              float* __restrict__ dst,
                                              int K, int chunk) {
  __shared__ float lds[2176];
  float* base = bias ? dst : dst + (size_t)blockIdx.z * 262144;
  gemm_dev(lds, A, W, bias, base, K, chunk,
           blockIdx.x * 64, blockIdx.y * 64, blockIdx.z * chunk);
}

// merged P0+P1 for iter 0: grid 320 1-D. b<256: xp partials (v_t@Wx). b>=256: x_in = inputs@Wp+bp.
__global__ __launch_bounds__(256) void k_gemm0(const float* __restrict__ v_t,
                                               const float* __restrict__ Wx,
                                               float* __restrict__ part,
                                               const float* __restrict__ inputs,
                                               const float* __restrict__ Wp,
                                               const float* __restrict__ bp,
                                               float* __restrict__ x_in) {
  __shared__ float lds[2176];
  const int b = blockIdx.x;
  if (b < 256) {
    int mt = b & 15, ntile = (b >> 4) & 3, kz = b >> 6;
    gemm_dev(lds, v_t, Wx, nullptr, part + (size_t)kz * 262144, 256, 64,
             mt * 64, ntile * 64, kz * 64);
  } else {
    int idx = b - 256;  // 0..63
    int mt = idx & 15, ntile = idx >> 4;
    gemm_dev(lds, inputs, Wp, bp, x_in, 128, 128, mt * 64, ntile * 64, 0);
  }
}

// fused adjacency: grid (8, 8, 4), block 256.
__global__ __launch_bounds__(256) void k_adj(const float* __restrict__ part,
                                             const float* __restrict__ incold,
                                             const float* __restrict__ wi,
                                             const float* __restrict__ bi,
                                             const float* __restrict__ bx,
                                             const float* __restrict__ wsv,
                                             const float* __restrict__ bs,
                                             float* __restrict__ pred,
                                             float* __restrict__ pred2) {
  __shared__ float lds[8448];
  float* tn = lds;
  float* te = lds + 32 * 132;
  const int n0 = blockIdx.x * 32, e0 = blockIdx.y * 32, gb = blockIdx.z;
  const int tid = threadIdx.x;
  const size_t rb = (size_t)gb * 256;
  const int tx = tid & 15, ty = tid >> 4;
  float incv[2][2], acc[2][2];
#pragma unroll
  for (int j = 0; j < 2; ++j)
#pragma unroll
    for (int i = 0; i < 2; ++i) {
      incv[j][i] = incold[((rb + e0 + ty + 16 * j) << 8) + n0 + tx + 16 * i];
      acc[j][i] = 0.f;
    }
  for (int dh = 0; dh < 256; dh += 128) {
    if (dh) __syncthreads();
#pragma unroll
    for (int s = 0; s < 4; ++s) {
      int idx = tid + s * 256;
      int row = idx >> 5;
      int d = dh + (idx & 31) * 4;
      float4 bxv = ld4(&bx[d]);
      {
        size_t o = ((rb + n0 + row) << 8) + d;
        float4 p0 = ld4(&part[o]);
        float4 p1 = ld4(&part[o + 262144]);
        float4 p2 = ld4(&part[o + 524288]);
        float4 p3 = ld4(&part[o + 786432]);
        float4 v;
        v.x = p0.x + p1.x + p2.x + p3.x + bxv.x;
        v.y = p0.y + p1.y + p2.y + p3.y + bxv.y;
        v.z = p0.z + p1.z + p2.z + p3.z + bxv.z;
        v.w = p0.w + p1.w + p2.w + p3.w + bxv.w;
        st4(&tn[row * 132 + (d - dh)], v);
      }
      {
        size_t o = ((rb + e0 + row) << 8) + d;
        float4 p0 = ld4(&part[o]);
        float4 p1 = ld4(&part[o + 262144]);
        float4 p2 = ld4(&part[o + 524288]);
        float4 p3 = ld4(&part[o + 786432]);
        float4 bv = ld4(&bi[d]);
        float4 v;
        v.x = p0.x + p1.x + p2.x + p3.x + bxv.x + bv.x;
        v.y = p0.y + p1.y + p2.y + p3.y + bxv.y + bv.y;
        v.z = p0.z + p1.z + p2.z + p3.z + bxv.z + bv.z;
        v.w = p0.w + p1.w + p2.w + p3.w + bxv.w + bv.w;
        st4(&te[row * 132 + (d - dh)], v);
      }
    }
    __syncthreads();
#pragma unroll 4
    for (int dl = 0; dl < 128; dl += 4) {
      float4 wiq = ld4(&wi[dh + dl]);
      float4 wsq = ld4(&wsv[dh + dl]);
      float4 xn0 = ld4(&tn[tx * 132 + dl]);
      float4 xn1 = ld4(&tn[(tx + 16) * 132 + dl]);
      float4 xe0 = ld4(&te[ty * 132 + dl]);
      float4 xe1 = ld4(&te[(ty + 16) * 132 + dl]);
#pragma unroll
      for (int j = 0; j < 2; ++j) {
        float4 xe = j ? xe1 : xe0;
#pragma unroll
        for (int i = 0; i < 2; ++i) {
          float4 xn = i ? xn1 : xn0;
          float u;
          u = fmaf(incv[j][i], wiq.x, xn.x + xe.x); u = fmaxf(u, 0.f); acc[j][i] = fmaf(u, wsq.x, acc[j][i]);
          u = fmaf(incv[j][i], wiq.y, xn.y + xe.y); u = fmaxf(u, 0.f); acc[j][i] = fmaf(u, wsq.y, acc[j][i]);
          u = fmaf(incv[j][i], wiq.z, xn.z + xe.z); u = fmaxf(u, 0.f); acc[j][i] = fmaf(u, wsq.z, acc[j][i]);
          u = fmaf(incv[j][i], wiq.w, xn.w + xe.w); u = fmaxf(u, 0.f); acc[j][i] = fmaf(u, wsq.w, acc[j][i]);
        }
      }
    }
  }
  const float b0 = bs[0];
#pragma unroll
  for (int j = 0; j < 2; ++j)
#pragma unroll
    for (int i = 0; i < 2; ++i) {
      float s = acc[j][i] + b0;
      float v = 1.f / (1.f + __expf(-s));
      size_t o = ((rb + e0 + ty + 16 * j) << 8) + n0 + tx + 16 * i;
      pred[o] = v;
      if (pred2) pred2[o] = v;
    }
}

// transposed-A GEMM: grid (4 ntiles, 4 ctiles, 16 = gb*4+kc), block 256.
__global__ __launch_bounds__(256) void k_gemmt(const float* __restrict__ pred,
                                               const float* __restrict__ nt,
                                               float* __restrict__ part) {
  __shared__ float lds[2176];
  const int gb = blockIdx.z >> 2, kc = blockIdx.z & 3;
  gemmt_dev(lds, pred, nt, part + (size_t)kc * 262144,
            gb, blockIdx.x * 64, blockIdx.y * 64, kc * 64);
}

// reduce upd partials + LN(concat) -> h. grid 256, block 256.
__global__ __launch_bounds__(256) void k_ln768(const float* __restrict__ part,
                                               const float* __restrict__ x_in,
                                               const float* __restrict__ nt,
                                               const float* __restrict__ g,
                                               const float* __restrict__ be,
                                               float* __restrict__ h) {
  const int row = blockIdx.x * 4 + (threadIdx.x >> 6);
  const int lane = threadIdx.x & 63;
  const int c4 = lane * 4;
  const size_t ro = (size_t)row * 256 + c4;
  float4 u = ld4(&part[ro]);
  float4 u1 = ld4(&part[ro + 262144]);
  float4 u2 = ld4(&part[ro + 524288]);
  float4 u3 = ld4(&part[ro + 786432]);
  u.x += u1.x + u2.x + u3.x;
  u.y += u1.y + u2.y + u3.y;
  u.z += u1.z + u2.z + u3.z;
  u.w += u1.w + u2.w + u3.w;
  float4 xi = ld4(&x_in[ro]);
  float4 nv = ld4(&nt[ro]);
  float s = xi.x + xi.y + xi.z + xi.w + nv.x + nv.y + nv.z + nv.w + u.x + u.y + u.z + u.w;
  float sq = xi.x * xi.x + xi.y * xi.y + xi.z * xi.z + xi.w * xi.w
           + nv.x * nv.x + nv.y * nv.y + nv.z * nv.z + nv.w * nv.w
           + u.x * u.x + u.y * u.y + u.z * u.z + u.w * u.w;
  wred2(s, sq);
  float mu = s * (1.f / 768.f);
  float rs = rsqrtf(sq * (1.f / 768.f) - mu * mu + LN_EPS);
  float* hr = h + (size_t)row * 768;
  {
    float4 g4 = ld4(&g[c4]), b4 = ld4(&be[c4]), o;
    o.x = (xi.x - mu) * rs * g4.x + b4.x;
    o.y = (xi.y - mu) * rs * g4.y + b4.y;
    o.z = (xi.z - mu) * rs * g4.z + b4.z;
    o.w = (xi.w - mu) * rs * g4.w + b4.w;
    st4(&hr[c4], o);
  }
  {
    float4 g4 = ld4(&g[256 + c4]), b4 = ld4(&be[256 + c4]), o;
    o.x = (nv.x - mu) * rs * g4.x + b4.x;
    o.y = (nv.y - mu) * rs * g4.y + b4.y;
    o.z = (nv.z - mu) * rs * g4.z + b4.z;
    o.w = (nv.w - mu) * rs * g4.w + b4.w;
    st4(&hr[256 + c4], o);
  }
  {
    float4 g4 = ld4(&g[512 + c4]), b4 = ld4(&be[512 + c4]), o;
    o.x = (u.x - mu) * rs * g4.x + b4.x;
    o.y = (u.y - mu) * rs * g4.y + b4.y;
    o.z = (u.z - mu) * rs * g4.z + b4.z;
    o.w = (u.w - mu) * rs * g4.w + b4.w;
    st4(&hr[512 + c4], o);
  }
}

// gemm768 (h @ W1g -> part) + mt1 partials, 1-D grid 304, block 256.
__global__ __launch_bounds__(256) void k_g768mtk(const float* __restrict__ h,
                                                 const float* __restrict__ W1g,
                                                 const float* __restrict__ W1l,
                                                 const float* __restrict__ b1,
                                                 float* __restrict__ part,
                                                 float* __restrict__ mt1p) {
  __shared__ float lds[2176];
  const int b = blockIdx.x;
  if (b < 256) {
    int mt = b & 15, ntile = (b >> 4) & 3, kz = b >> 6;
    gemm_dev(lds, h, W1g, nullptr, part + (size_t)kz * 262144, 768, 192,
             mt * 64, ntile * 64, kz * 192);
  } else {
    int idx = b - 256;           // 0..47
    mtk_dev(lds, h, W1l, b1, mt1p, idx & 3, idx >> 2, 768);
  }
}

// gemm_h1 (relu(h1) @ W2g -> part2) + mt2 partials, 1-D grid 272, block 256.
__global__ __launch_bounds__(256) void k_gh1mtk2(const float* __restrict__ part,
                                                 const float* __restrict__ mt1p,
                                                 const float* __restrict__ W2g,
                                                 const float* __restrict__ W2l,
                                                 const float* __restrict__ b2,
                                                 float* __restrict__ part2,
                                                 float* __restrict__ mt2p) {
  __shared__ float lds[2240];
  const int b = blockIdx.x;
  if (b < 256) {
    int mt = b & 15, ntile = (b >> 4) & 3, kz = b >> 6;
    gemm_h1(lds, part, mt1p, W2g, part2 + (size_t)kz * 262144,
            mt >> 2, mt * 64, ntile * 64, kz * 64);
  } else {
    int idx = b - 256;           // 0..15
    mtk_h1(lds, part, mt1p, W2l, b2, mt2p, idx & 3, idx >> 2);
  }
}

// reduce part2 partials + mt2 + residual + LN -> dst. grid 256, block 256.
__global__ __launch_bounds__(256) void k_ln256(const float* __restrict__ part2,
                                               const float* __restrict__ nt,
                                               const float* __restrict__ mt2p,
                                               const float* __restrict__ g,
                                               const float* __restrict__ be,
                                               float* __restrict__ dst) {
  const int row = blockIdx.x * 4 + (threadIdx.x >> 6);
  const int lane = threadIdx.x & 63;
  const int c4 = lane * 4;
  const int gb = row >> 8;
  const size_t ro = (size_t)row * 256 + c4;
  float4 p0 = ld4(&part2[ro]);
  float4 p1 = ld4(&part2[ro + 262144]);
  float4 p2 = ld4(&part2[ro + 524288]);
  float4 p3 = ld4(&part2[ro + 786432]);
  float4 m4 = {0.f, 0.f, 0.f, 0.f};
#pragma unroll
  for (int k2 = 0; k2 < 4; ++k2) {
    float4 mv = ld4(&mt2p[((size_t)(k2 * 4 + gb) << 8) + c4]);
    m4.x += mv.x; m4.y += mv.y; m4.z += mv.z; m4.w += mv.w;
  }
  float4 nv = ld4(&nt[ro]);
  float4 x;
  x.x = nv.x + p0.x + p1.x + p2.x + p3.x + m4.x;
  x.y = nv.y + p0.y + p1.y + p2.y + p3.y + m4.y;
  x.z = nv.z + p0.z + p1.z + p2.z + p3.z + m4.z;
  x.w = nv.w + p0.w + p1.w + p2.w + p3.w + m4.w;
  float s = x.x + x.y + x.z + x.w;
  float sq = x.x * x.x + x.y * x.y + x.z * x.z + x.w * x.w;
  wred2(s, sq);
  float mu = s * (1.f / 256.f);
  float rs = rsqrtf(sq * (1.f / 256.f) - mu * mu + LN_EPS);
  float4 g4 = ld4(&g[c4]), b4 = ld4(&be[c4]), o;
  o.x = (x.x - mu) * rs * g4.x + b4.x;
  o.y = (x.y - mu) * rs * g4.y + b4.y;
  o.z = (x.z - mu) * rs * g4.z + b4.z;
  o.w = (x.w - mu) * rs * g4.w + b4.w;
  st4(&dst[ro], o);
}

extern "C" void kernel_launch(void* const* d_in, const int* in_sizes, int n_in,
                              void* d_out, int out_size, void* d_ws, size_t ws_size,
                              hipStream_t stream) {
  (void)in_sizes; (void)n_in; (void)out_size; (void)ws_size;
  const float* inputs = (const float*)d_in[0];
  const float* v_t    = (const float*)d_in[1];
  const float* i_t    = (const float*)d_in[2];
  const float* Wp     = (const float*)d_in[3];
  const float* bp     = (const float*)d_in[4];
  const float* Wx     = (const float*)d_in[5];
  const float* bx     = (const float*)d_in[6];
  const float* wi     = (const float*)d_in[7];
  const float* bi     = (const float*)d_in[8];
  const float* ws     = (const float*)d_in[9];
  const float* bs     = (const float*)d_in[10];
  const float* g_pre  = (const float*)d_in[11];
  const float* be_pre = (const float*)d_in[12];
  const float* g_n    = (const float*)d_in[13];
  const float* be_n   = (const float*)d_in[14];
  const float* W1g    = (const float*)d_in[15];
  const float* W1l    = (const float*)d_in[16];
  const float* b1     = (const float*)d_in[17];
  const float* W2g    = (const float*)d_in[18];
  const float* W2l    = (const float*)d_in[19];
  const float* b2     = (const float*)d_in[20];
  float* out = (float*)d_out;
  float* wsf = (float*)d_ws;
  float* x_in  = wsf;                  // 1 MB
  float* ntA   = wsf + 262144;         // 1 MB
  float* ntB   = wsf + 524288;         // 1 MB
  float* h     = wsf + 786432;         // 3 MB (dead after k_g768mtk)
  float* part2 = wsf + 786432;         // 4 MB = h + old-h1 region
  float* part  = wsf + 1835008;        // 4 MB
  float* mt1p  = wsf + 2883584;        // 48 KB
  float* mt2p  = wsf + 2895872;        // 16 KB

  for (int t = 0; t < 3; ++t) {
    const float* ntCur = (t == 0) ? v_t : ((t == 1) ? ntA : ntB);
    float* dstNt = (t == 2) ? (out + 786432) : ((t == 0) ? ntA : ntB);
    const float* incold = (t == 0) ? i_t : (out + (size_t)(t - 1) * 262144);
    float* pred = out + (size_t)t * 262144;
    float* pred2 = (t == 2) ? (out + 1048576) : nullptr;

    // P1: xp partials = ntCur @ Wx (K-split 4); at t=0 also P0 (x_in) as extra blocks
    if (t == 0) {
      k_gemm0<<<320, 256, 0, stream>>>(v_t, Wx, part, inputs, Wp, bp, x_in);
    } else {
      k_gemm<<<dim3(16, 4, 4), 256, 0, stream>>>(ntCur, Wx, nullptr, part, 256, 64);
    }
    // P2: inc = sigmoid(sum_d relu(xp[n]+xp[e]+bi + inc*wi) * ws + bs)
    k_adj<<<dim3(8, 8, 4), 256, 0, stream>>>(part, incold, wi, bi, bx, ws, bs, pred, pred2);
    // P3: upd partials = pred^T @ ntCur (e-split 4)
    k_gemmt<<<dim3(4, 4, 16), 256, 0, stream>>>(pred, ntCur, part);
    // P4: h = LN(concat(x_in, nt, upd))
    k_ln768<<<256, 256, 0, stream>>>(part, x_in, ntCur, g_pre, be_pre, h);
    // P5: gemm768 partials + mt1 partials (one dispatch)
    k_g768mtk<<<304, 256, 0, stream>>>(h, W1g, W1l, b1, part, mt1p);
    // P6: part2 partials = relu(h1 inline) @ W2g + mt2 partials (one dispatch)
    k_gh1mtk2<<<272, 256, 0, stream>>>(part, mt1p, W2g, W2l, b2, part2, mt2p);
    // P7: nt' = LN(nt + sum part2 + mt2)
    k_ln256<<<256, 256, 0, stream>>>(part2, ntCur, mt2p, g_n, be_n, dstNt);
  }
}

// Round 8
// 193.205 us; speedup vs baseline: 4.7296x; 1.0279x over previous
//
#include <hip/hip_runtime.h>
#include <cstddef>

#define LN_EPS 1e-5f

__device__ inline float4 ld4(const float* p) { return *reinterpret_cast<const float4*>(p); }
__device__ inline void st4(float* p, float4 v) { *reinterpret_cast<float4*>(p) = v; }

typedef _Float16 h2_t __attribute__((ext_vector_type(2)));

__device__ __forceinline__ unsigned pack2(float x, float y) {
  h2_t h;
  h.x = (_Float16)x;
  h.y = (_Float16)y;
  return __builtin_bit_cast(unsigned, h);
}

// dot2: c += a.x*b.x + a.y*b.y  (f16 inputs, f32 accumulate)
__device__ __forceinline__ float dot2(unsigned a, unsigned b, float c) {
  h2_t ah = __builtin_bit_cast(h2_t, a);
  h2_t bh = __builtin_bit_cast(h2_t, b);
#if __has_builtin(__builtin_amdgcn_fdot2)
  return __builtin_amdgcn_fdot2(ah, bh, c, false);
#else
  return fmaf((float)ah.x, (float)bh.x, fmaf((float)ah.y, (float)bh.y, c));
#endif
}

// ---- 64x64 tile GEMM, f16 LDS (k-pair packed), 4x4 micro, KSTEP 16, pipelined.
// LDS: AtU [8 kk2][68] (pairs x rows), WsU [8 kk2][68] (pairs x cols). 1088 uints.
// A role: all 256 threads (1 row x 4 k). W role: tid<128 (1 pair-row x 4 cols).
__device__ __forceinline__ void gemm16(unsigned* ldsU, const float* __restrict__ A,
                                       const float* __restrict__ W,
                                       const float* __restrict__ bias,
                                       float* __restrict__ dst,
                                       int K, int chunk, int row0, int col0, int k0) {
  unsigned* AtU = ldsU;
  unsigned* WsU = ldsU + 544;
  const int tid = threadIdx.x;
  const int tx = tid & 15, ty = tid >> 4;
  const int arow = tid >> 2, ak4 = (tid & 3) * 4;
  const int wkk2 = tid >> 4, wc4 = (tid & 15) * 4;  // valid when tid<128
  float acc[4][4] = {{0.f}};
  float4 av = ld4(&A[(size_t)(row0 + arow) * K + k0 + ak4]);
  float4 w0, w1;
  if (tid < 128) {
    w0 = ld4(&W[(size_t)(k0 + 2 * wkk2) * 256 + col0 + wc4]);
    w1 = ld4(&W[(size_t)(k0 + 2 * wkk2 + 1) * 256 + col0 + wc4]);
  }
  for (int ks = 0; ks < chunk; ks += 16) {
    __syncthreads();
    AtU[(ak4 >> 1) * 68 + arow] = pack2(av.x, av.y);
    AtU[((ak4 >> 1) + 1) * 68 + arow] = pack2(av.z, av.w);
    if (tid < 128) {
      WsU[wkk2 * 68 + wc4 + 0] = pack2(w0.x, w1.x);
      WsU[wkk2 * 68 + wc4 + 1] = pack2(w0.y, w1.y);
      WsU[wkk2 * 68 + wc4 + 2] = pack2(w0.z, w1.z);
      WsU[wkk2 * 68 + wc4 + 3] = pack2(w0.w, w1.w);
    }
    __syncthreads();
    if (ks + 16 < chunk) {
      av = ld4(&A[(size_t)(row0 + arow) * K + k0 + ks + 16 + ak4]);
      if (tid < 128) {
        w0 = ld4(&W[(size_t)(k0 + ks + 16 + 2 * wkk2) * 256 + col0 + wc4]);
        w1 = ld4(&W[(size_t)(k0 + ks + 16 + 2 * wkk2 + 1) * 256 + col0 + wc4]);
      }
    }
#pragma unroll
    for (int kk2 = 0; kk2 < 8; ++kk2) {
      uint4 a4 = *reinterpret_cast<const uint4*>(&AtU[kk2 * 68 + ty * 4]);
      uint4 w4 = *reinterpret_cast<const uint4*>(&WsU[kk2 * 68 + tx * 4]);
      acc[0][0] = dot2(a4.x, w4.x, acc[0][0]); acc[0][1] = dot2(a4.x, w4.y, acc[0][1]);
      acc[0][2] = dot2(a4.x, w4.z, acc[0][2]); acc[0][3] = dot2(a4.x, w4.w, acc[0][3]);
      acc[1][0] = dot2(a4.y, w4.x, acc[1][0]); acc[1][1] = dot2(a4.y, w4.y, acc[1][1]);
      acc[1][2] = dot2(a4.y, w4.z, acc[1][2]); acc[1][3] = dot2(a4.y, w4.w, acc[1][3]);
      acc[2][0] = dot2(a4.z, w4.x, acc[2][0]); acc[2][1] = dot2(a4.z, w4.y, acc[2][1]);
      acc[2][2] = dot2(a4.z, w4.z, acc[2][2]); acc[2][3] = dot2(a4.z, w4.w, acc[2][3]);
      acc[3][0] = dot2(a4.w, w4.x, acc[3][0]); acc[3][1] = dot2(a4.w, w4.y, acc[3][1]);
      acc[3][2] = dot2(a4.w, w4.z, acc[3][2]); acc[3][3] = dot2(a4.w, w4.w, acc[3][3]);
    }
  }
  if (bias) {
    float4 b4 = ld4(&bias[col0 + tx * 4]);
#pragma unroll
    for (int i = 0; i < 4; ++i) {
      float4 o;
      o.x = acc[i][0] + b4.x; o.y = acc[i][1] + b4.y;
      o.z = acc[i][2] + b4.z; o.w = acc[i][3] + b4.w;
      st4(&dst[(size_t)(row0 + ty * 4 + i) * 256 + col0 + tx * 4], o);
    }
  } else {
#pragma unroll
    for (int i = 0; i < 4; ++i) {
      float4 o = {acc[i][0], acc[i][1], acc[i][2], acc[i][3]};
      st4(&dst[(size_t)(row0 + ty * 4 + i) * 256 + col0 + tx * 4], o);
    }
  }
}

// ---- transposed-A batched GEMM (upd), f16 LDS, pairs along e. batch gb.
// Role split: tid<128 stage A(pred), tid>=128 stage B(nt); each 1 pair-row x 4 cols.
__device__ __forceinline__ void gemmt16(unsigned* ldsU, const float* __restrict__ pred,
                                        const float* __restrict__ nt,
                                        float* __restrict__ pp,
                                        int gb, int n0, int col0, int k0) {
  unsigned* AtU = ldsU;
  unsigned* WsU = ldsU + 544;
  const int tid = threadIdx.x;
  const int tx = tid & 15, ty = tid >> 4;
  const float* Ab = pred + ((size_t)gb << 16);
  const float* Bb = nt + ((size_t)gb << 16);
  const int t7 = tid & 127;
  const int ee2 = t7 >> 4, cg4 = (t7 & 15) * 4;
  const int base = (tid < 128) ? n0 : col0;
  const float* src = (tid < 128) ? Ab : Bb;
  unsigned* dstU = (tid < 128) ? AtU : WsU;
  float acc[4][4] = {{0.f}};
  float4 r0 = ld4(&src[((size_t)(k0 + 2 * ee2) << 8) + base + cg4]);
  float4 r1 = ld4(&src[((size_t)(k0 + 2 * ee2 + 1) << 8) + base + cg4]);
  for (int ks = 0; ks < 64; ks += 16) {
    __syncthreads();
    dstU[ee2 * 68 + cg4 + 0] = pack2(r0.x, r1.x);
    dstU[ee2 * 68 + cg4 + 1] = pack2(r0.y, r1.y);
    dstU[ee2 * 68 + cg4 + 2] = pack2(r0.z, r1.z);
    dstU[ee2 * 68 + cg4 + 3] = pack2(r0.w, r1.w);
    __syncthreads();
    if (ks + 16 < 64) {
      r0 = ld4(&src[((size_t)(k0 + ks + 16 + 2 * ee2) << 8) + base + cg4]);
      r1 = ld4(&src[((size_t)(k0 + ks + 16 + 2 * ee2 + 1) << 8) + base + cg4]);
    }
#pragma unroll
    for (int kk2 = 0; kk2 < 8; ++kk2) {
      uint4 a4 = *reinterpret_cast<const uint4*>(&AtU[kk2 * 68 + ty * 4]);
      uint4 w4 = *reinterpret_cast<const uint4*>(&WsU[kk2 * 68 + tx * 4]);
      acc[0][0] = dot2(a4.x, w4.x, acc[0][0]); acc[0][1] = dot2(a4.x, w4.y, acc[0][1]);
      acc[0][2] = dot2(a4.x, w4.z, acc[0][2]); acc[0][3] = dot2(a4.x, w4.w, acc[0][3]);
      acc[1][0] = dot2(a4.y, w4.x, acc[1][0]); acc[1][1] = dot2(a4.y, w4.y, acc[1][1]);
      acc[1][2] = dot2(a4.y, w4.z, acc[1][2]); acc[1][3] = dot2(a4.y, w4.w, acc[1][3]);
      acc[2][0] = dot2(a4.z, w4.x, acc[2][0]); acc[2][1] = dot2(a4.z, w4.y, acc[2][1]);
      acc[2][2] = dot2(a4.z, w4.z, acc[2][2]); acc[2][3] = dot2(a4.z, w4.w, acc[2][3]);
      acc[3][0] = dot2(a4.w, w4.x, acc[3][0]); acc[3][1] = dot2(a4.w, w4.y, acc[3][1]);
      acc[3][2] = dot2(a4.w, w4.z, acc[3][2]); acc[3][3] = dot2(a4.w, w4.w, acc[3][3]);
    }
  }
#pragma unroll
  for (int i = 0; i < 4; ++i) {
    float4 o = {acc[i][0], acc[i][1], acc[i][2], acc[i][3]};
    st4(&pp[(((size_t)gb << 8) + n0 + ty * 4 + i) * 256 + col0 + tx * 4], o);
  }
}

// ---- 64x64 GEMM, A = h1 recomputed inline: relu(sum_4 part slabs + mt1), f16 LDS.
__device__ __forceinline__ void gemm_h116(unsigned* ldsU, const float* __restrict__ part,
                                          const float* __restrict__ mt1p,
                                          const float* __restrict__ W,
                                          float* __restrict__ dst,
                                          int gb, int row0, int col0, int k0) {
  unsigned* AtU = ldsU;
  unsigned* WsU = ldsU + 544;
  float* mt1s = reinterpret_cast<float*>(ldsU + 1088);  // [64]
  const int tid = threadIdx.x;
  const int tx = tid & 15, ty = tid >> 4;
  const int arow = tid >> 2, ak4 = (tid & 3) * 4;
  const int wkk2 = tid >> 4, wc4 = (tid & 15) * 4;
  if (tid < 64) {
    float s = 0.f;
#pragma unroll
    for (int k2 = 0; k2 < 12; ++k2) s += mt1p[((size_t)(k2 * 4 + gb) << 8) + k0 + tid];
    mt1s[tid] = s;
  }
  float acc[4][4] = {{0.f}};
  size_t ao = (size_t)(row0 + arow) * 256 + k0 + ak4;
  float4 p0 = ld4(&part[ao]);
  float4 p1 = ld4(&part[ao + 262144]);
  float4 p2 = ld4(&part[ao + 524288]);
  float4 p3 = ld4(&part[ao + 786432]);
  float4 w0, w1;
  if (tid < 128) {
    w0 = ld4(&W[(size_t)(k0 + 2 * wkk2) * 256 + col0 + wc4]);
    w1 = ld4(&W[(size_t)(k0 + 2 * wkk2 + 1) * 256 + col0 + wc4]);
  }
  for (int ks = 0; ks < 64; ks += 16) {
    __syncthreads();   // also makes mt1s visible on first pass
    float4 m = ld4(&mt1s[ks + ak4]);
    float ax = fmaxf(p0.x + p1.x + p2.x + p3.x + m.x, 0.f);
    float ay = fmaxf(p0.y + p1.y + p2.y + p3.y + m.y, 0.f);
    float az = fmaxf(p0.z + p1.z + p2.z + p3.z + m.z, 0.f);
    float aw = fmaxf(p0.w + p1.w + p2.w + p3.w + m.w, 0.f);
    AtU[(ak4 >> 1) * 68 + arow] = pack2(ax, ay);
    AtU[((ak4 >> 1) + 1) * 68 + arow] = pack2(az, aw);
    if (tid < 128) {
      WsU[wkk2 * 68 + wc4 + 0] = pack2(w0.x, w1.x);
      WsU[wkk2 * 68 + wc4 + 1] = pack2(w0.y, w1.y);
      WsU[wkk2 * 68 + wc4 + 2] = pack2(w0.z, w1.z);
      WsU[wkk2 * 68 + wc4 + 3] = pack2(w0.w, w1.w);
    }
    __syncthreads();
    if (ks + 16 < 64) {
      size_t an = (size_t)(row0 + arow) * 256 + k0 + ks + 16 + ak4;
      p0 = ld4(&part[an]);
      p1 = ld4(&part[an + 262144]);
      p2 = ld4(&part[an + 524288]);
      p3 = ld4(&part[an + 786432]);
      if (tid < 128) {
        w0 = ld4(&W[(size_t)(k0 + ks + 16 + 2 * wkk2) * 256 + col0 + wc4]);
        w1 = ld4(&W[(size_t)(k0 + ks + 16 + 2 * wkk2 + 1) * 256 + col0 + wc4]);
      }
    }
#pragma unroll
    for (int kk2 = 0; kk2 < 8; ++kk2) {
      uint4 a4 = *reinterpret_cast<const uint4*>(&AtU[kk2 * 68 + ty * 4]);
      uint4 w4 = *reinterpret_cast<const uint4*>(&WsU[kk2 * 68 + tx * 4]);
      acc[0][0] = dot2(a4.x, w4.x, acc[0][0]); acc[0][1] = dot2(a4.x, w4.y, acc[0][1]);
      acc[0][2] = dot2(a4.x, w4.z, acc[0][2]); acc[0][3] = dot2(a4.x, w4.w, acc[0][3]);
      acc[1][0] = dot2(a4.y, w4.x, acc[1][0]); acc[1][1] = dot2(a4.y, w4.y, acc[1][1]);
      acc[1][2] = dot2(a4.y, w4.z, acc[1][2]); acc[1][3] = dot2(a4.y, w4.w, acc[1][3]);
      acc[2][0] = dot2(a4.z, w4.x, acc[2][0]); acc[2][1] = dot2(a4.z, w4.y, acc[2][1]);
      acc[2][2] = dot2(a4.z, w4.z, acc[2][2]); acc[2][3] = dot2(a4.z, w4.w, acc[2][3]);
      acc[3][0] = dot2(a4.w, w4.x, acc[3][0]); acc[3][1] = dot2(a4.w, w4.y, acc[3][1]);
      acc[3][2] = dot2(a4.w, w4.z, acc[3][2]); acc[3][3] = dot2(a4.w, w4.w, acc[3][3]);
    }
  }
#pragma unroll
  for (int i = 0; i < 4; ++i) {
    float4 o = {acc[i][0], acc[i][1], acc[i][2], acc[i][3]};
    st4(&dst[(size_t)(row0 + ty * 4 + i) * 256 + col0 + tx * 4], o);
  }
}

__device__ __forceinline__ void wred2(float& s, float& q) {
#pragma unroll
  for (int off = 32; off; off >>= 1) {
    s += __shfl_xor(s, off);
    q += __shfl_xor(q, off);
  }
}

// ---- colmean(64-col slice of X) + mean-linear partial (f32).
__device__ __forceinline__ void mtk_dev(float* lds, const float* __restrict__ X,
                                        const float* __restrict__ Wl,
                                        const float* __restrict__ bias,
                                        float* __restrict__ mtp, int gb, int ks, int Kd) {
  float* sm = lds;
  float* m64 = lds + 256;
  const int tid = threadIdx.x;
  const int col = tid & 63, q = tid >> 6;
  const float* xb = X + (size_t)(gb * 256 + q * 64) * Kd + ks * 64 + col;
  float s = 0.f;
#pragma unroll 8
  for (int r = 0; r < 64; ++r) s += xb[(size_t)r * Kd];
  sm[tid] = s;
  __syncthreads();
  if (tid < 64) m64[tid] = (sm[tid] + sm[tid + 64] + sm[tid + 128] + sm[tid + 192]) * (1.f / 256.f);
  __syncthreads();
  const int c = tid;
  float acc = (ks == 0) ? bias[c] : 0.f;
  const float* wp = Wl + (size_t)ks * 64 * 256 + c;
#pragma unroll 8
  for (int k = 0; k < 64; ++k) acc = fmaf(m64[k], wp[(size_t)k * 256], acc);
  mtp[((size_t)(ks * 4 + gb) << 8) + c] = acc;
}

// ---- colmean of h1 (recomputed inline: relu(sum part slabs + mt1)) + W2l partial (f32).
__device__ __forceinline__ void mtk_h1(float* lds, const float* __restrict__ part,
                                       const float* __restrict__ mt1p,
                                       const float* __restrict__ Wl,
                                       const float* __restrict__ bias,
                                       float* __restrict__ mtp, int gb, int ks) {
  float* sm = lds;
  float* m64 = lds + 256;
  const int tid = threadIdx.x;
  const int col = tid & 63, q = tid >> 6;
  float mt1v = 0.f;
#pragma unroll
  for (int k2 = 0; k2 < 12; ++k2) mt1v += mt1p[((size_t)(k2 * 4 + gb) << 8) + ks * 64 + col];
  const float* pb = part + (size_t)(gb * 256 + q * 64) * 256 + ks * 64 + col;
  float s = 0.f;
#pragma unroll 4
  for (int r = 0; r < 64; ++r) {
    size_t o = (size_t)r * 256;
    float v = pb[o] + pb[o + 262144] + pb[o + 524288] + pb[o + 786432] + mt1v;
    s += fmaxf(v, 0.f);
  }
  sm[tid] = s;
  __syncthreads();
  if (tid < 64) m64[tid] = (sm[tid] + sm[tid + 64] + sm[tid + 128] + sm[tid + 192]) * (1.f / 256.f);
  __syncthreads();
  const int c = tid;
  float acc = (ks == 0) ? bias[c] : 0.f;
  const float* wp = Wl + (size_t)ks * 64 * 256 + c;
#pragma unroll 8
  for (int k = 0; k < 64; ++k) acc = fmaf(m64[k], wp[(size_t)k * 256], acc);
  mtp[((size_t)(ks * 4 + gb) << 8) + c] = acc;
}

// ================== kernels ==================

// gemm: grid (16 mtiles, 4 ntiles, KS), block 256.
__global__ __launch_bounds__(256) void k_gemm(const float* __restrict__ A,
                                              const float* __restrict__ W,
                                              const float* __restrict__ bias,
                                              float* __restrict__ dst,
                                              int K, int chunk) {
  __shared__ unsigned ldsU[1088];
  float* base = bias ? dst : dst + (size_t)blockIdx.z * 262144;
  gemm16(ldsU, A, W, bias, base, K, chunk,
         blockIdx.x * 64, blockIdx.y * 64, blockIdx.z * chunk);
}

// merged P0+P1 for iter 0: grid 320 1-D. b<256: xp partials (v_t@Wx). b>=256: x_in.
__global__ __launch_bounds__(256) void k_gemm0(const float* __restrict__ v_t,
                                               const float* __restrict__ Wx,
                                               float* __restrict__ part,
                                               const float* __restrict__ inputs,
                                               const float* __restrict__ Wp,
                                               const float* __restrict__ bp,
                                               float* __restrict__ x_in) {
  __shared__ unsigned ldsU[1088];
  const int b = blockIdx.x;
  if (b < 256) {
    int mt = b & 15, ntile = (b >> 4) & 3, kz = b >> 6;
    gemm16(ldsU, v_t, Wx, nullptr, part + (size_t)kz * 262144, 256, 64,
           mt * 64, ntile * 64, kz * 64);
  } else {
    int idx = b - 256;  // 0..63
    int mt = idx & 15, ntile = idx >> 4;
    gemm16(ldsU, inputs, Wp, bp, x_in, 128, 128, mt * 64, ntile * 64, 0);
  }
}

// fused adjacency (f32, verified): grid (8, 8, 4), block 256.
__global__ __launch_bounds__(256) void k_adj(const float* __restrict__ part,
                                             const float* __restrict__ incold,
                                             const float* __restrict__ wi,
                                             const float* __restrict__ bi,
                                             const float* __restrict__ bx,
                                             const float* __restrict__ wsv,
                                             const float* __restrict__ bs,
                                             float* __restrict__ pred,
                                             float* __restrict__ pred2) {
  __shared__ float lds[8448];
  float* tn = lds;
  float* te = lds + 32 * 132;
  const int n0 = blockIdx.x * 32, e0 = blockIdx.y * 32, gb = blockIdx.z;
  const int tid = threadIdx.x;
  const size_t rb = (size_t)gb * 256;
  const int tx = tid & 15, ty = tid >> 4;
  float incv[2][2], acc[2][2];
#pragma unroll
  for (int j = 0; j < 2; ++j)
#pragma unroll
    for (int i = 0; i < 2; ++i) {
      incv[j][i] = incold[((rb + e0 + ty + 16 * j) << 8) + n0 + tx + 16 * i];
      acc[j][i] = 0.f;
    }
  for (int dh = 0; dh < 256; dh += 128) {
    if (dh) __syncthreads();
#pragma unroll
    for (int s = 0; s < 4; ++s) {
      int idx = tid + s * 256;
      int row = idx >> 5;
      int d = dh + (idx & 31) * 4;
      float4 bxv = ld4(&bx[d]);
      {
        size_t o = ((rb + n0 + row) << 8) + d;
        float4 p0 = ld4(&part[o]);
        float4 p1 = ld4(&part[o + 262144]);
        float4 p2 = ld4(&part[o + 524288]);
        float4 p3 = ld4(&part[o + 786432]);
        float4 v;
        v.x = p0.x + p1.x + p2.x + p3.x + bxv.x;
        v.y = p0.y + p1.y + p2.y + p3.y + bxv.y;
        v.z = p0.z + p1.z + p2.z + p3.z + bxv.z;
        v.w = p0.w + p1.w + p2.w + p3.w + bxv.w;
        st4(&tn[row * 132 + (d - dh)], v);
      }
      {
        size_t o = ((rb + e0 + row) << 8) + d;
        float4 p0 = ld4(&part[o]);
        float4 p1 = ld4(&part[o + 262144]);
        float4 p2 = ld4(&part[o + 524288]);
        float4 p3 = ld4(&part[o + 786432]);
        float4 bv = ld4(&bi[d]);
        float4 v;
        v.x = p0.x + p1.x + p2.x + p3.x + bxv.x + bv.x;
        v.y = p0.y + p1.y + p2.y + p3.y + bxv.y + bv.y;
        v.z = p0.z + p1.z + p2.z + p3.z + bxv.z + bv.z;
        v.w = p0.w + p1.w + p2.w + p3.w + bxv.w + bv.w;
        st4(&te[row * 132 + (d - dh)], v);
      }
    }
    __syncthreads();
#pragma unroll 4
    for (int dl = 0; dl < 128; dl += 4) {
      float4 wiq = ld4(&wi[dh + dl]);
      float4 wsq = ld4(&wsv[dh + dl]);
      float4 xn0 = ld4(&tn[tx * 132 + dl]);
      float4 xn1 = ld4(&tn[(tx + 16) * 132 + dl]);
      float4 xe0 = ld4(&te[ty * 132 + dl]);
      float4 xe1 = ld4(&te[(ty + 16) * 132 + dl]);
#pragma unroll
      for (int j = 0; j < 2; ++j) {
        float4 xe = j ? xe1 : xe0;
#pragma unroll
        for (int i = 0; i < 2; ++i) {
          float4 xn = i ? xn1 : xn0;
          float u;
          u = fmaf(incv[j][i], wiq.x, xn.x + xe.x); u = fmaxf(u, 0.f); acc[j][i] = fmaf(u, wsq.x, acc[j][i]);
          u = fmaf(incv[j][i], wiq.y, xn.y + xe.y); u = fmaxf(u, 0.f); acc[j][i] = fmaf(u, wsq.y, acc[j][i]);
          u = fmaf(incv[j][i], wiq.z, xn.z + xe.z); u = fmaxf(u, 0.f); acc[j][i] = fmaf(u, wsq.z, acc[j][i]);
          u = fmaf(incv[j][i], wiq.w, xn.w + xe.w); u = fmaxf(u, 0.f); acc[j][i] = fmaf(u, wsq.w, acc[j][i]);
        }
      }
    }
  }
  const float b0 = bs[0];
#pragma unroll
  for (int j = 0; j < 2; ++j)
#pragma unroll
    for (int i = 0; i < 2; ++i) {
      float s = acc[j][i] + b0;
      float v = 1.f / (1.f + __expf(-s));
      size_t o = ((rb + e0 + ty + 16 * j) << 8) + n0 + tx + 16 * i;
      pred[o] = v;
      if (pred2) pred2[o] = v;
    }
}

// transposed-A GEMM: grid (4 ntiles, 4 ctiles, 16 = gb*4+kc), block 256.
__global__ __launch_bounds__(256) void k_gemmt(const float* __restrict__ pred,
                                               const float* __restrict__ nt,
                                               float* __restrict__ part) {
  __shared__ unsigned ldsU[1088];
  const int gb = blockIdx.z >> 2, kc = blockIdx.z & 3;
  gemmt16(ldsU, pred, nt, part + (size_t)kc * 262144,
          gb, blockIdx.x * 64, blockIdx.y * 64, kc * 64);
}

// reduce upd partials + LN(concat) -> h. grid 256, block 256.
__global__ __launch_bounds__(256) void k_ln768(const float* __restrict__ part,
                                               const float* __restrict__ x_in,
                                               const float* __restrict__ nt,
                                               const float* __restrict__ g,
                                               const float* __restrict__ be,
                                               float* __restrict__ h) {
  const int row = blockIdx.x * 4 + (threadIdx.x >> 6);
  const int lane = threadIdx.x & 63;
  const int c4 = lane * 4;
  const size_t ro = (size_t)row * 256 + c4;
  float4 u = ld4(&part[ro]);
  float4 u1 = ld4(&part[ro + 262144]);
  float4 u2 = ld4(&part[ro + 524288]);
  float4 u3 = ld4(&part[ro + 786432]);
  u.x += u1.x + u2.x + u3.x;
  u.y += u1.y + u2.y + u3.y;
  u.z += u1.z + u2.z + u3.z;
  u.w += u1.w + u2.w + u3.w;
  float4 xi = ld4(&x_in[ro]);
  float4 nv = ld4(&nt[ro]);
  float s = xi.x + xi.y + xi.z + xi.w + nv.x + nv.y + nv.z + nv.w + u.x + u.y + u.z + u.w;
  float sq = xi.x * xi.x + xi.y * xi.y + xi.z * xi.z + xi.w * xi.w
           + nv.x * nv.x + nv.y * nv.y + nv.z * nv.z + nv.w * nv.w
           + u.x * u.x + u.y * u.y + u.z * u.z + u.w * u.w;
  wred2(s, sq);
  float mu = s * (1.f / 768.f);
  float rs = rsqrtf(sq * (1.f / 768.f) - mu * mu + LN_EPS);
  float* hr = h + (size_t)row * 768;
  {
    float4 g4 = ld4(&g[c4]), b4 = ld4(&be[c4]), o;
    o.x = (xi.x - mu) * rs * g4.x + b4.x;
    o.y = (xi.y - mu) * rs * g4.y + b4.y;
    o.z = (xi.z - mu) * rs * g4.z + b4.z;
    o.w = (xi.w - mu) * rs * g4.w + b4.w;
    st4(&hr[c4], o);
  }
  {
    float4 g4 = ld4(&g[256 + c4]), b4 = ld4(&be[256 + c4]), o;
    o.x = (nv.x - mu) * rs * g4.x + b4.x;
    o.y = (nv.y - mu) * rs * g4.y + b4.y;
    o.z = (nv.z - mu) * rs * g4.z + b4.z;
    o.w = (nv.w - mu) * rs * g4.w + b4.w;
    st4(&hr[256 + c4], o);
  }
  {
    float4 g4 = ld4(&g[512 + c4]), b4 = ld4(&be[512 + c4]), o;
    o.x = (u.x - mu) * rs * g4.x + b4.x;
    o.y = (u.y - mu) * rs * g4.y + b4.y;
    o.z = (u.z - mu) * rs * g4.z + b4.z;
    o.w = (u.w - mu) * rs * g4.w + b4.w;
    st4(&hr[512 + c4], o);
  }
}

// gemm768 (h @ W1g -> part) + mt1 partials, 1-D grid 304, block 256.
__global__ __launch_bounds__(256) void k_g768mtk(const float* __restrict__ h,
                                                 const float* __restrict__ W1g,
                                                 const float* __restrict__ W1l,
                                                 const float* __restrict__ b1,
                                                 float* __restrict__ part,
                                                 float* __restrict__ mt1p) {
  __shared__ unsigned ldsU[1088];
  const int b = blockIdx.x;
  if (b < 256) {
    int mt = b & 15, ntile = (b >> 4) & 3, kz = b >> 6;
    gemm16(ldsU, h, W1g, nullptr, part + (size_t)kz * 262144, 768, 192,
           mt * 64, ntile * 64, kz * 192);
  } else {
    int idx = b - 256;           // 0..47
    mtk_dev(reinterpret_cast<float*>(ldsU), h, W1l, b1, mt1p, idx & 3, idx >> 2, 768);
  }
}

// gemm_h1 (relu(h1) @ W2g -> part2) + mt2 partials, 1-D grid 272, block 256.
__global__ __launch_bounds__(256) void k_gh1mtk2(const float* __restrict__ part,
                                                 const float* __restrict__ mt1p,
                                                 const float* __restrict__ W2g,
                                                 const float* __restrict__ W2l,
                                                 const float* __restrict__ b2,
                                                 float* __restrict__ part2,
                                                 float* __restrict__ mt2p) {
  __shared__ unsigned ldsU[1152];
  const int b = blockIdx.x;
  if (b < 256) {
    int mt = b & 15, ntile = (b >> 4) & 3, kz = b >> 6;
    gemm_h116(ldsU, part, mt1p, W2g, part2 + (size_t)kz * 262144,
              mt >> 2, mt * 64, ntile * 64, kz * 64);
  } else {
    int idx = b - 256;           // 0..15
    mtk_h1(reinterpret_cast<float*>(ldsU), part, mt1p, W2l, b2, mt2p, idx & 3, idx >> 2);
  }
}

// reduce part2 partials + mt2 + residual + LN -> dst. grid 256, block 256.
__global__ __launch_bounds__(256) void k_ln256(const float* __restrict__ part2,
                                               const float* __restrict__ nt,
                                               const float* __restrict__ mt2p,
                                               const float* __restrict__ g,
                                               const float* __restrict__ be,
                                               float* __restrict__ dst) {
  const int row = blockIdx.x * 4 + (threadIdx.x >> 6);
  const int lane = threadIdx.x & 63;
  const int c4 = lane * 4;
  const int gb = row >> 8;
  const size_t ro = (size_t)row * 256 + c4;
  float4 p0 = ld4(&part2[ro]);
  float4 p1 = ld4(&part2[ro + 262144]);
  float4 p2 = ld4(&part2[ro + 524288]);
  float4 p3 = ld4(&part2[ro + 786432]);
  float4 m4 = {0.f, 0.f, 0.f, 0.f};
#pragma unroll
  for (int k2 = 0; k2 < 4; ++k2) {
    float4 mv = ld4(&mt2p[((size_t)(k2 * 4 + gb) << 8) + c4]);
    m4.x += mv.x; m4.y += mv.y; m4.z += mv.z; m4.w += mv.w;
  }
  float4 nv = ld4(&nt[ro]);
  float4 x;
  x.x = nv.x + p0.x + p1.x + p2.x + p3.x + m4.x;
  x.y = nv.y + p0.y + p1.y + p2.y + p3.y + m4.y;
  x.z = nv.z + p0.z + p1.z + p2.z + p3.z + m4.z;
  x.w = nv.w + p0.w + p1.w + p2.w + p3.w + m4.w;
  float s = x.x + x.y + x.z + x.w;
  float sq = x.x * x.x + x.y * x.y + x.z * x.z + x.w * x.w;
  wred2(s, sq);
  float mu = s * (1.f / 256.f);
  float rs = rsqrtf(sq * (1.f / 256.f) - mu * mu + LN_EPS);
  float4 g4 = ld4(&g[c4]), b4 = ld4(&be[c4]), o;
  o.x = (x.x - mu) * rs * g4.x + b4.x;
  o.y = (x.y - mu) * rs * g4.y + b4.y;
  o.z = (x.z - mu) * rs * g4.z + b4.z;
  o.w = (x.w - mu) * rs * g4.w + b4.w;
  st4(&dst[ro], o);
}

extern "C" void kernel_launch(void* const* d_in, const int* in_sizes, int n_in,
                              void* d_out, int out_size, void* d_ws, size_t ws_size,
                              hipStream_t stream) {
  (void)in_sizes; (void)n_in; (void)out_size; (void)ws_size;
  const float* inputs = (const float*)d_in[0];
  const float* v_t    = (const float*)d_in[1];
  const float* i_t    = (const float*)d_in[2];
  const float* Wp     = (const float*)d_in[3];
  const float* bp     = (const float*)d_in[4];
  const float* Wx     = (const float*)d_in[5];
  const float* bx     = (const float*)d_in[6];
  const float* wi     = (const float*)d_in[7];
  const float* bi     = (const float*)d_in[8];
  const float* ws     = (const float*)d_in[9];
  const float* bs     = (const float*)d_in[10];
  const float* g_pre  = (const float*)d_in[11];
  const float* be_pre = (const float*)d_in[12];
  const float* g_n    = (const float*)d_in[13];
  const float* be_n   = (const float*)d_in[14];
  const float* W1g    = (const float*)d_in[15];
  const float* W1l    = (const float*)d_in[16];
  const float* b1     = (const float*)d_in[17];
  const float* W2g    = (const float*)d_in[18];
  const float* W2l    = (const float*)d_in[19];
  const float* b2     = (const float*)d_in[20];
  float* out = (float*)d_out;
  float* wsf = (float*)d_ws;
  float* x_in  = wsf;                  // 1 MB
  float* ntA   = wsf + 262144;         // 1 MB
  float* ntB   = wsf + 524288;         // 1 MB
  float* h     = wsf + 786432;         // 3 MB (dead after k_g768mtk)
  float* part2 = wsf + 786432;         // 4 MB = h + old-h1 region
  float* part  = wsf + 1835008;        // 4 MB
  float* mt1p  = wsf + 2883584;        // 48 KB
  float* mt2p  = wsf + 2895872;        // 16 KB

  for (int t = 0; t < 3; ++t) {
    const float* ntCur = (t == 0) ? v_t : ((t == 1) ? ntA : ntB);
    float* dstNt = (t == 2) ? (out + 786432) : ((t == 0) ? ntA : ntB);
    const float* incold = (t == 0) ? i_t : (out + (size_t)(t - 1) * 262144);
    float* pred = out + (size_t)t * 262144;
    float* pred2 = (t == 2) ? (out + 1048576) : nullptr;

    // P1: xp partials = ntCur @ Wx (K-split 4); at t=0 also x_in as extra blocks
    if (t == 0) {
      k_gemm0<<<320, 256, 0, stream>>>(v_t, Wx, part, inputs, Wp, bp, x_in);
    } else {
      k_gemm<<<dim3(16, 4, 4), 256, 0, stream>>>(ntCur, Wx, nullptr, part, 256, 64);
    }
    // P2: inc = sigmoid(sum_d relu(xp[n]+xp[e]+bi + inc*wi) * ws + bs)
    k_adj<<<dim3(8, 8, 4), 256, 0, stream>>>(part, incold, wi, bi, bx, ws, bs, pred, pred2);
    // P3: upd partials = pred^T @ ntCur (e-split 4)
    k_gemmt<<<dim3(4, 4, 16), 256, 0, stream>>>(pred, ntCur, part);
    // P4: h = LN(concat(x_in, nt, upd))
    k_ln768<<<256, 256, 0, stream>>>(part, x_in, ntCur, g_pre, be_pre, h);
    // P5: gemm768 partials + mt1 partials (one dispatch)
    k_g768mtk<<<304, 256, 0, stream>>>(h, W1g, W1l, b1, part, mt1p);
    // P6: part2 partials = relu(h1 inline) @ W2g + mt2 partials (one dispatch)
    k_gh1mtk2<<<272, 256, 0, stream>>>(part, mt1p, W2g, W2l, b2, part2, mt2p);
    // P7: nt' = LN(nt + sum part2 + mt2)
    k_ln256<<<256, 256, 0, stream>>>(part2, ntCur, mt2p, g_n, be_n, dstNt);
  }
}